// Round 5
// baseline (1166.027 us; speedup 1.0000x reference)
//
#include <hip/hip_runtime.h>

// ============================================================================
// VQ-VAE forward, MI355X fp32. Internal layout NHWC; outputs NCHW.
// B=4096. x(4096,1,28,28) -> h1(4096,14,14,32) -> h2(4096,7,7,64)
//   -> z -> VQ(512 codes, D=64) -> d0 -> d1(4096,14,14,32) -> recon.
// VQ argmin reproduces np fp32 semantics exactly:
//   dist = fl( fl(SZ + SC_k) - 2*dot(z,c_k) ), SZ/SC via numpy pairwise-8,
//   dot via sequential-K fma (BLAS order), first-min-wins tie break.
// R2: unrolled tap loop -> 256-VGPR cap -> scratch spill -> 12 GB HBM.
// R4: k2/k6 were LDS-read bound -> s_load weights + polyphase LDS x + big
//   register tiles, barrier-free K loops.
// R6 (REVERTED): per-thread-contiguous global access is catastrophic.
// R7: global-cb vector loads: L2-stream bound. R8: cb LDS chunks, 2pt/thr:
//   VGPR=164, 421us, Occ 9% -> latency-bound.
// R9-R11: 1pt/thr 784 blocks; zr never promoted (VGPR=52): with z tile live
//   in LDS the compiler sinks zr reads into the k loop. asm pins and
//   launch_bounds(256,3) both failed to move VGPR_Count.
// R12: cb chunks clobber z tile -> zr leaves LDS, 316us, VALU 64.5%. BUT
//   VGPR=64 + no scratch => zr spilled to AGPRs (legacy heuristic), each fma
//   pays v_accvgpr_read: VALU-busy 204us = 2.4x the 84us fma floor. LDS
//   broadcast reads (~160us) co-limit.
// R13 (this round): (1) codebook via inline-asm s_load_dwordx16 into SGPRs
//   (wave-uniform rows -> scalar pipe; v_fmac reads SGPR operand directly),
//   NO LDS in k loop; z tile volatile-clobbered after extraction so zr
//   cannot be re-read (explicit replacement for R12's chunk-clobber).
//   (2) amdgpu_waves_per_eu(3,4) replaces launch_bounds minwaves (RA ignored
//   it): 170-VGPR budget -> zr in arch VGPRs, no AGPR moves.
//   Gate: k4 VGPR_Count must rise to ~100+.
// Workspace (floats): h1/d1 @0 (25,690,112) | h2/zq @25,690,112 (12,845,056)
//   | z/d0 @38,535,168 (12,845,056) | cn @51,380,224 (512) | loss @51,380,736
// Out (floats): recon@0, z@3,211,264, z_q@16,056,320, loss@28,901,376,
//   idx@28,901,377 (200,704)
// ============================================================================

#define NB 4096

typedef float sf16 __attribute__((ext_vector_type(16)));

__device__ __forceinline__ float4 f4fma(float s, float4 w, float4 a) {
  a.x = fmaf(s, w.x, a.x); a.y = fmaf(s, w.y, a.y);
  a.z = fmaf(s, w.z, a.z); a.w = fmaf(s, w.w, a.w);
  return a;
}
__device__ __forceinline__ float4 f4relu(float4 a) {
  a.x = fmaxf(a.x, 0.f); a.y = fmaxf(a.y, 0.f);
  a.z = fmaxf(a.z, 0.f); a.w = fmaxf(a.w, 0.f);
  return a;
}
__device__ __forceinline__ float4 f4addrn(float4 a, float4 b) {
  a.x = __fadd_rn(a.x, b.x); a.y = __fadd_rn(a.y, b.y);
  a.z = __fadd_rn(a.z, b.z); a.w = __fadd_rn(a.w, b.w);
  return a;
}

// numpy pairwise-8 sum of squares over 64 contiguous values
__device__ __forceinline__ float np_sumsq64(const float* v) {
  float r[8];
#pragma unroll
  for (int j = 0; j < 8; ++j) r[j] = __fmul_rn(v[j], v[j]);
#pragma unroll
  for (int i = 8; i < 64; i += 8)
#pragma unroll
    for (int j = 0; j < 8; ++j) r[j] = __fadd_rn(r[j], __fmul_rn(v[i + j], v[i + j]));
  return __fadd_rn(__fadd_rn(__fadd_rn(r[0], r[1]), __fadd_rn(r[2], r[3])),
                   __fadd_rn(__fadd_rn(r[4], r[5]), __fadd_rn(r[6], r[7])));
}

// ---- K0: codebook norms (numpy-order) + zero loss accumulator --------------
__global__ __launch_bounds__(256) void k0_init(const float* __restrict__ cb,
                                               float* __restrict__ cn,
                                               float* __restrict__ loss) {
  int t = threadIdx.x;
  if (t == 0) *loss = 0.f;
  for (int k = t; k < 512; k += 256) cn[k] = np_sumsq64(&cb[k * 64]);
}

// ---- K1: conv1 4x4 s2 p1, 1->32, bias-after, ReLU. out h1 NHWC -------------
__global__ __launch_bounds__(256) void k1_conv1(const float* __restrict__ x,
                                                const float* __restrict__ w1,
                                                const float* __restrict__ b1,
                                                float* __restrict__ h1) {
  __shared__ float xs[784];
  __shared__ float wl[512];
  __shared__ float bs[32];
  int n = blockIdx.x, t = threadIdx.x;
  for (int j = t; j < 784; j += 256) xs[j] = x[n * 784 + j];
  for (int j = t; j < 512; j += 256) wl[j] = w1[j];
  if (t < 32) bs[t] = b1[t];
  __syncthreads();
  int c = t & 31, pg = t >> 5;
  for (int s = pg; s < 196; s += 8) {
    int oh = s / 14, ow = s % 14;
    float acc = 0.f;
#pragma unroll
    for (int kh = 0; kh < 4; ++kh) {
      int ih = 2 * oh - 1 + kh;
      if (ih < 0 || ih >= 28) continue;
#pragma unroll
      for (int kw = 0; kw < 4; ++kw) {
        int iw = 2 * ow - 1 + kw;
        if (iw < 0 || iw >= 28) continue;
        acc = fmaf(xs[ih * 28 + iw], wl[(kh * 4 + kw) * 32 + c], acc);
      }
    }
    acc = __fadd_rn(acc, bs[c]);
    h1[(n * 196 + s) * 32 + c] = fmaxf(acc, 0.f);
  }
}

// ---- K2: conv2 4x4 s2 p1, 32->64, bias-after, ReLU. NHWC -------------------
__global__ __launch_bounds__(256) void k2_conv2(const float* __restrict__ h1,
                                                const float* __restrict__ w2,
                                                const float* __restrict__ b2,
                                                float* __restrict__ h2) {
  __shared__ float4 xs4[2 * 2049];
  int nb = blockIdx.x, t = threadIdx.x;
  size_t n0 = (size_t)nb * 2;
  for (int j = t; j < 4098; j += 256) xs4[j] = make_float4(0.f, 0.f, 0.f, 0.f);
  __syncthreads();
  for (int j = t; j < 1568; j += 256) {
    int p = j >> 3, c4 = j & 7;
    int ihp = p / 14 + 1, iwp = p % 14 + 1;
    int chunk = (c4 * 16 + ihp) * 16 + (iwp & 1) * 8 + (iwp >> 1);
    xs4[chunk] = *(const float4*)(h1 + n0 * 6272 + p * 32 + c4 * 4);
    xs4[2049 + chunk] = *(const float4*)(h1 + (n0 + 1) * 6272 + p * 32 + c4 * 4);
  }
  __syncthreads();
  int l = t & 63;
  int co0 = __builtin_amdgcn_readfirstlane((t >> 6) * 16);
  int img = l >> 5, pt = l & 31;
  int oh0 = pt >> 3, ow = pt & 7;
  int imgoff = img * 2049;
  bool v0 = (ow < 7);
  bool v1 = (ow < 7) && (oh0 + 4 < 7);
  float4 A0[4], A1[4];
#pragma unroll
  for (int g = 0; g < 4; ++g) { A0[g] = make_float4(0.f, 0.f, 0.f, 0.f); A1[g] = A0[g]; }
#pragma unroll 1
  for (int kk = 0; kk < 16; ++kk) {
    int kh = kk >> 2, kw = kk & 3;
    int cc = 2 * ow + kw; if (cc > 15) cc = 15;
    int off = (cc & 1) * 8 + (cc >> 1);
    int rc0 = 2 * oh0 + kh;
    int rc1 = rc0 + 8; if (rc1 > 15) rc1 = 15;
    int b0 = imgoff + rc0 * 16 + off;
    int b1 = imgoff + rc1 * 16 + off;
    int wb = __builtin_amdgcn_readfirstlane(kk * 2048 + co0);
#pragma unroll 2
    for (int c4 = 0; c4 < 8; ++c4) {
      float4 x0 = xs4[b0 + c4 * 256];
      float4 x1 = xs4[b1 + c4 * 256];
      float xa0[4] = {x0.x, x0.y, x0.z, x0.w};
      float xa1[4] = {x1.x, x1.y, x1.z, x1.w};
      const float* wk = w2 + wb + c4 * 256;
#pragma unroll
      for (int j = 0; j < 4; ++j) {
#pragma unroll
        for (int g = 0; g < 4; ++g) {
          float4 wv4;
          wv4.x = wk[j * 64 + g * 4 + 0]; wv4.y = wk[j * 64 + g * 4 + 1];
          wv4.z = wk[j * 64 + g * 4 + 2]; wv4.w = wk[j * 64 + g * 4 + 3];
          A0[g] = f4fma(xa0[j], wv4, A0[g]);
          A1[g] = f4fma(xa1[j], wv4, A1[g]);
        }
      }
    }
  }
  float4 bias[4];
#pragma unroll
  for (int g = 0; g < 4; ++g) bias[g] = *(const float4*)&b2[co0 + g * 4];
  if (v0) {
    size_t ob = ((n0 + img) * 49 + oh0 * 7 + ow) * 64 + co0;
#pragma unroll
    for (int g = 0; g < 4; ++g)
      *(float4*)&h2[ob + g * 4] = f4relu(f4addrn(A0[g], bias[g]));
  }
  if (v1) {
    size_t ob = ((n0 + img) * 49 + (oh0 + 4) * 7 + ow) * 64 + co0;
#pragma unroll
    for (int g = 0; g < 4; ++g)
      *(float4*)&h2[ob + g * 4] = f4relu(f4addrn(A1[g], bias[g]));
  }
}

// ---- K_pw: 1x1 conv 64->64, bias-after (no act). NHWC ----------------------
__global__ __launch_bounds__(256) void k_pw(const float* __restrict__ xin,
                                            const float* __restrict__ w,     // [ci][co]
                                            const float* __restrict__ bias,
                                            float* __restrict__ yout) {
  __shared__ float tile[256 * 65];
  int t = threadIdx.x;
  long m0 = (long)blockIdx.x * 256;
  for (int j = t; j < 16384; j += 256) tile[(j >> 6) * 65 + (j & 63)] = xin[m0 * 64 + j];
  __syncthreads();
  float xr[64];
#pragma unroll
  for (int ci = 0; ci < 64; ++ci) xr[ci] = tile[t * 65 + ci];
  for (int g = 0; g < 4; ++g) {
    float4 z4 = make_float4(0.f, 0.f, 0.f, 0.f);
    float4 a0 = z4, a1 = z4, a2 = z4, a3 = z4;
#pragma unroll
    for (int ci = 0; ci < 64; ++ci) {
      float xv = xr[ci];
      const float* wr = &w[ci * 64 + g * 16];
      a0 = f4fma(xv, *(const float4*)&wr[0], a0);
      a1 = f4fma(xv, *(const float4*)&wr[4], a1);
      a2 = f4fma(xv, *(const float4*)&wr[8], a2);
      a3 = f4fma(xv, *(const float4*)&wr[12], a3);
    }
    a0 = f4addrn(a0, *(const float4*)&bias[g * 16 + 0]);
    a1 = f4addrn(a1, *(const float4*)&bias[g * 16 + 4]);
    a2 = f4addrn(a2, *(const float4*)&bias[g * 16 + 8]);
    a3 = f4addrn(a3, *(const float4*)&bias[g * 16 + 12]);
    float* dst = &tile[t * 65 + g * 16];
    dst[0] = a0.x; dst[1] = a0.y; dst[2] = a0.z; dst[3] = a0.w;
    dst[4] = a1.x; dst[5] = a1.y; dst[6] = a1.z; dst[7] = a1.w;
    dst[8] = a2.x; dst[9] = a2.y; dst[10] = a2.z; dst[11] = a2.w;
    dst[12] = a3.x; dst[13] = a3.y; dst[14] = a3.z; dst[15] = a3.w;
  }
  __syncthreads();
  for (int j = t; j < 16384; j += 256) yout[m0 * 64 + j] = tile[(j >> 6) * 65 + (j & 63)];
}

// ---- K4: VQ. 256 points/block (1/thread). cb rows via s_load -> SGPRs ------
// 784 blocks. zr[64] in arch VGPRs (waves_per_eu(3,4) budget; z tile
// volatile-clobbered after extraction so LDS remat is illegal). k loop:
// 4x s_load_dwordx16 (scalar pipe, wave-uniform row) + 64 v_fmac with SGPR
// src -- no LDS, no VMEM. Sequential-ci fma chain, ascending-k first-min.
__global__ __launch_bounds__(256)
__attribute__((amdgpu_waves_per_eu(3, 4)))
void k4_vq(const float* __restrict__ zin,
           const float* __restrict__ cb,
           const float* __restrict__ cn,
           float* __restrict__ zq_nhwc,
           float* __restrict__ outz,
           float* __restrict__ outzq,
           float* __restrict__ outidx,
           float* __restrict__ loss) {
  __shared__ float lds[8320];   // 128*65 staging tile
  __shared__ float red[4];
  int t = threadIdx.x;
  size_t m0 = (size_t)blockIdx.x * 256;
  float zr[64];

  // stage-in: two 128-row tiles, coalesced global -> LDS -> registers
#pragma unroll
  for (int S = 0; S < 2; ++S) {
    __syncthreads();
    const float* src = zin + (m0 + S * 128) * 64;
    for (int j4 = t; j4 < 2048; j4 += 256) {
      int row = j4 >> 4, col = (j4 & 15) * 4;
      *(float4*)&lds[row * 65 + col] = *(const float4*)(src + j4 * 4);
    }
    __syncthreads();
    if ((t >> 7) == S) {
      int r = t & 127;
#pragma unroll
      for (int ci = 0; ci < 64; ci += 4) {
        float4 v = *(float4*)&lds[r * 65 + ci];
        zr[ci] = v.x; zr[ci + 1] = v.y; zr[ci + 2] = v.z; zr[ci + 3] = v.w;
      }
    }
  }
  __syncthreads();
  // Clobber the z tile (volatile: cannot be DCE'd) so the compiler cannot
  // re-materialize zr from LDS inside the k loop (R9 lesson, now explicit
  // since the cb chunks no longer overwrite the tile).
  {
    volatile float* vl = lds;
    for (int j = t; j < 8320; j += 256) vl[j] = 0.f;
  }
#pragma unroll
  for (int ci = 0; ci < 64; ++ci) asm volatile("" : "+v"(zr[ci]));

  float sz = np_sumsq64(zr);
  float mind = 3.4e38f;
  int mi = 0;
  const float* cbp = cb;
#pragma unroll 1
  for (int k = 0; k < 512; ++k) {
    sf16 A, B, C, D;
    asm volatile(
        "s_load_dwordx16 %0, %4, 0x0\n\t"
        "s_load_dwordx16 %1, %4, 0x40\n\t"
        "s_load_dwordx16 %2, %4, 0x80\n\t"
        "s_load_dwordx16 %3, %4, 0xC0\n\t"
        "s_waitcnt lgkmcnt(0)"
        : "=&s"(A), "=&s"(B), "=&s"(C), "=&s"(D)
        : "s"(cbp));
    float d0 = 0.f;
#pragma unroll
    for (int j = 0; j < 16; ++j) d0 = fmaf(zr[j], A[j], d0);
#pragma unroll
    for (int j = 0; j < 16; ++j) d0 = fmaf(zr[16 + j], B[j], d0);
#pragma unroll
    for (int j = 0; j < 16; ++j) d0 = fmaf(zr[32 + j], C[j], d0);
#pragma unroll
    for (int j = 0; j < 16; ++j) d0 = fmaf(zr[48 + j], D[j], d0);
    float q0 = __fsub_rn(__fadd_rn(sz, cn[k]), __fmul_rn(2.f, d0));
    if (q0 < mind) { mind = q0; mi = k; }
    cbp += 64;
  }

  // idx + z NCHW scatter (zr still live)
  outidx[m0 + t] = (float)mi;
  {
    unsigned mA = (unsigned)(m0 + t);
    unsigned nA = mA / 49u, spA = mA % 49u;
    float* zo = outz + (size_t)nA * 3136 + spA;
#pragma unroll
    for (int ci = 0; ci < 64; ++ci) zo[ci * 49] = zr[ci];
  }

  float lsum = 0.f;
#pragma unroll
  for (int S = 0; S < 2; ++S) {
    __syncthreads();
    if ((t >> 7) == S) {
      int r = t & 127;
      unsigned mm = (unsigned)(m0 + S * 128 + r);
      unsigned nn = mm / 49u, ss = mm % 49u;
      float* qo = outzq + (size_t)nn * 3136 + ss;
      const float* qr = cb + (size_t)mi * 64;
#pragma unroll
      for (int ci = 0; ci < 64; ci += 4) {
        float4 q4 = *(const float4*)(qr + ci);
        *(float4*)&lds[r * 65 + ci] = q4;
        qo[(ci + 0) * 49] = q4.x; qo[(ci + 1) * 49] = q4.y;
        qo[(ci + 2) * 49] = q4.z; qo[(ci + 3) * 49] = q4.w;
        float e0 = q4.x - zr[ci], e1 = q4.y - zr[ci + 1];
        float e2 = q4.z - zr[ci + 2], e3 = q4.w - zr[ci + 3];
        lsum = fmaf(e0, e0, lsum); lsum = fmaf(e1, e1, lsum);
        lsum = fmaf(e2, e2, lsum); lsum = fmaf(e3, e3, lsum);
      }
    }
    __syncthreads();
    float* dstg = zq_nhwc + (m0 + S * 128) * 64;
    for (int j4 = t; j4 < 2048; j4 += 256) {
      int row = j4 >> 4, col = (j4 & 15) * 4;
      *(float4*)(dstg + j4 * 4) = *(float4*)&lds[row * 65 + col];
    }
  }
#pragma unroll
  for (int off = 32; off > 0; off >>= 1) lsum += __shfl_down(lsum, off);
  int wid = t >> 6, lane = t & 63;
  if (lane == 0) red[wid] = lsum;
  __syncthreads();
  if (t == 0) atomicAdd(loss, red[0] + red[1] + red[2] + red[3]);
}

// ---- K4b: finalize loss ----------------------------------------------------
__global__ __launch_bounds__(64) void k_lossfin(const float* __restrict__ loss,
                                                float* __restrict__ out) {
  if (threadIdx.x == 0) out[0] = loss[0] * (1.25f / 12845056.f);
}

// ---- K6: deconv1 4x4 s2 p2 (lhs_dilation), 64->32, ReLU. NHWC --------------
__global__ __launch_bounds__(256) void k6_deconv1(const float* __restrict__ d0,
                                                  const float* __restrict__ dw1,
                                                  const float* __restrict__ db1,
                                                  float* __restrict__ d1) {
  __shared__ float4 xs4[2 * 1297];
  int nb = blockIdx.x, t = threadIdx.x;
  size_t n0 = (size_t)nb * 2;
  for (int j = t; j < 2594; j += 256) xs4[j] = make_float4(0.f, 0.f, 0.f, 0.f);
  __syncthreads();
  for (int j = t; j < 784; j += 256) {
    int p = j >> 4, c4 = j & 15;
    int chunk = c4 * 81 + (p / 7 + 1) * 9 + (p % 7 + 1);
    xs4[chunk] = *(const float4*)(d0 + n0 * 3136 + p * 64 + c4 * 4);
    xs4[1297 + chunk] = *(const float4*)(d0 + (n0 + 1) * 3136 + p * 64 + c4 * 4);
  }
  __syncthreads();
  int l = t & 63;
  int ph = __builtin_amdgcn_readfirstlane(t >> 6);
  int ra = ph >> 1, rb = ph & 1;
  int img = l >> 5, pt = l & 31;
  bool v1 = (pt + 32 < 49);
  int p1 = v1 ? pt + 32 : 48;
  int mh0 = pt / 7, mw0 = pt % 7;
  int mh1 = p1 / 7, mw1 = p1 % 7;
  int imgoff = img * 1297;
  float4 A0[8], A1[8];
#pragma unroll
  for (int g = 0; g < 8; ++g) { A0[g] = make_float4(0.f, 0.f, 0.f, 0.f); A1[g] = A0[g]; }
#pragma unroll 1
  for (int tap = 0; tap < 4; ++tap) {
    int th = tap >> 1, tw = tap & 1;
    int kh = 2 * th + ra, kw = 2 * tw + rb;
    int b0 = imgoff + (mh0 + th + ra) * 9 + (mw0 + tw + rb);
    int b1 = imgoff + (mh1 + th + ra) * 9 + (mw1 + tw + rb);
    int wb = __builtin_amdgcn_readfirstlane((kh * 4 + kw) * 2048);
#pragma unroll 1
    for (int c4 = 0; c4 < 16; ++c4) {
      float4 x0 = xs4[b0 + c4 * 81];
      float4 x1 = xs4[b1 + c4 * 81];
      float xa0[4] = {x0.x, x0.y, x0.z, x0.w};
      float xa1[4] = {x1.x, x1.y, x1.z, x1.w};
      const float* wk = dw1 + wb + c4 * 128;
#pragma unroll
      for (int j = 0; j < 4; ++j) {
#pragma unroll
        for (int g = 0; g < 8; ++g) {
          float4 wv4;
          wv4.x = wk[j * 32 + g * 4 + 0]; wv4.y = wk[j * 32 + g * 4 + 1];
          wv4.z = wk[j * 32 + g * 4 + 2]; wv4.w = wk[j * 32 + g * 4 + 3];
          A0[g] = f4fma(xa0[j], wv4, A0[g]);
          A1[g] = f4fma(xa1[j], wv4, A1[g]);
        }
      }
    }
  }
  int oh0 = 2 * mh0 + ra, ow0 = 2 * mw0 + rb;
  size_t ob0 = ((n0 + img) * 196 + (size_t)(oh0 * 14 + ow0)) * 32;
#pragma unroll
  for (int g = 0; g < 8; ++g) {
    float4 bg = *(const float4*)&db1[g * 4];
    *(float4*)&d1[ob0 + g * 4] = f4relu(f4addrn(A0[g], bg));
  }
  if (v1) {
    int oh1 = 2 * mh1 + ra, ow1 = 2 * mw1 + rb;
    size_t ob1 = ((n0 + img) * 196 + (size_t)(oh1 * 14 + ow1)) * 32;
#pragma unroll
    for (int g = 0; g < 8; ++g) {
      float4 bg = *(const float4*)&db1[g * 4];
      *(float4*)&d1[ob1 + g * 4] = f4relu(f4addrn(A1[g], bg));
    }
  }
}

// ---- K7: deconv2 4x4 s2 p2, 32->1, sigmoid -> recon NCHW -------------------
__global__ __launch_bounds__(256) void k7_deconv2(const float* __restrict__ d1,
                                                  const float* __restrict__ dw2,
                                                  const float* __restrict__ db2,
                                                  float* __restrict__ recon) {
  __shared__ float xs[196 * 36];
  __shared__ float wl[512];
  int n = blockIdx.x, t = threadIdx.x;
  for (int j = t; j < 6272; j += 256) xs[(j >> 5) * 36 + (j & 31)] = d1[(size_t)n * 6272 + j];
  for (int j = t; j < 512; j += 256) wl[j] = dw2[j];
  __syncthreads();
  float bias = db2[0];
  for (int j = t; j < 392; j += 256) {
    int ra = j / 196, rem = j % 196;
    int mh = rem / 14, mw = rem % 14;
    float acc0 = bias, acc1 = bias;
    bool vm = (mw >= 1), vp = (mw + 1 < 14);
#pragma unroll
    for (int th = 0; th < 2; ++th) {
      int ih = mh + th - 1 + ra;
      if (ih < 0 || ih >= 14) continue;
      int kh = 2 * th + ra;
#pragma unroll
      for (int ci = 0; ci < 32; ci += 4) {
        float4 z4 = make_float4(0.f, 0.f, 0.f, 0.f);
        float4 xm = vm ? *(float4*)&xs[(ih * 14 + mw - 1) * 36 + ci] : z4;
        float4 x0 = *(float4*)&xs[(ih * 14 + mw) * 36 + ci];
        float4 xp = vp ? *(float4*)&xs[(ih * 14 + mw + 1) * 36 + ci] : z4;
        float4 wk0 = *(float4*)&wl[(kh * 4 + 0) * 32 + ci];
        float4 wk1 = *(float4*)&wl[(kh * 4 + 1) * 32 + ci];
        float4 wk2 = *(float4*)&wl[(kh * 4 + 2) * 32 + ci];
        float4 wk3 = *(float4*)&wl[(kh * 4 + 3) * 32 + ci];
        acc0 = fmaf(xm.x, wk0.x, acc0); acc0 = fmaf(xm.y, wk0.y, acc0);
        acc0 = fmaf(xm.z, wk0.z, acc0); acc0 = fmaf(xm.w, wk0.w, acc0);
        acc0 = fmaf(x0.x, wk2.x, acc0); acc0 = fmaf(x0.y, wk2.y, acc0);
        acc0 = fmaf(x0.z, wk2.z, acc0); acc0 = fmaf(x0.w, wk2.w, acc0);
        acc1 = fmaf(x0.x, wk1.x, acc1); acc1 = fmaf(x0.y, wk1.y, acc1);
        acc1 = fmaf(x0.z, wk1.z, acc1); acc1 = fmaf(x0.w, wk1.w, acc1);
        acc1 = fmaf(xp.x, wk3.x, acc1); acc1 = fmaf(xp.y, wk3.y, acc1);
        acc1 = fmaf(xp.z, wk3.z, acc1); acc1 = fmaf(xp.w, wk3.w, acc1);
      }
    }
    float r0 = 1.f / (1.f + __expf(-acc0));
    float r1 = 1.f / (1.f + __expf(-acc1));
    int oh = 2 * mh + ra;
    *(float2*)&recon[(size_t)n * 784 + oh * 28 + 2 * mw] = make_float2(r0, r1);
  }
}

extern "C" void kernel_launch(void* const* d_in, const int* in_sizes, int n_in,
                              void* d_out, int out_size, void* d_ws, size_t ws_size,
                              hipStream_t stream) {
  const float* x   = (const float*)d_in[0];
  const float* w1  = (const float*)d_in[1];
  const float* b1  = (const float*)d_in[2];
  const float* w2  = (const float*)d_in[3];
  const float* b2  = (const float*)d_in[4];
  const float* w3  = (const float*)d_in[5];
  const float* b3  = (const float*)d_in[6];
  const float* cb  = (const float*)d_in[7];
  const float* dw0 = (const float*)d_in[8];
  const float* db0 = (const float*)d_in[9];
  const float* dw1 = (const float*)d_in[10];
  const float* db1 = (const float*)d_in[11];
  const float* dw2 = (const float*)d_in[12];
  const float* db2 = (const float*)d_in[13];
  float* out = (float*)d_out;
  float* ws  = (float*)d_ws;

  float* h1   = ws;                 // 25,690,112 (reused as d1)
  float* h2   = ws + 25690112;      // 12,845,056 (reused as zq_nhwc)
  float* zb   = ws + 38535168;      // 12,845,056 z_nhwc (reused as d0)
  float* cn   = ws + 51380224;      // 512
  float* loss = ws + 51380736;      // 1

  float* recon   = out;
  float* zout    = out + 3211264;
  float* zqout   = out + 16056320;
  float* lossout = out + 28901376;
  float* idxout  = out + 28901377;

  k0_init<<<1, 256, 0, stream>>>(cb, cn, loss);
  k1_conv1<<<NB, 256, 0, stream>>>(x, w1, b1, h1);
  k2_conv2<<<NB / 2, 256, 0, stream>>>(h1, w2, b2, h2);
  k_pw<<<784, 256, 0, stream>>>(h2, w3, b3, zb);                 // z = h2 @ w3 + b3
  k4_vq<<<784, 256, 0, stream>>>(zb, cb, cn, h2, zout, zqout, idxout, loss);
  k_lossfin<<<1, 64, 0, stream>>>(loss, lossout);
  k_pw<<<784, 256, 0, stream>>>(h2, dw0, db0, zb);               // d0 = zq @ dw0 + db0
  k6_deconv1<<<NB / 2, 256, 0, stream>>>(zb, dw1, db1, h1);
  k7_deconv2<<<NB, 256, 0, stream>>>(h1, dw2, db2, recon);
}

// Round 6
// 1115.429 us; speedup vs baseline: 1.0454x; 1.0454x over previous
//
#include <hip/hip_runtime.h>

// ============================================================================
// VQ-VAE forward, MI355X fp32. Internal layout NHWC; outputs NCHW.
// B=4096. x(4096,1,28,28) -> h1(4096,14,14,32) -> h2(4096,7,7,64)
//   -> z -> VQ(512 codes, D=64) -> d0 -> d1(4096,14,14,32) -> recon.
// VQ argmin reproduces np fp32 semantics exactly:
//   dist = fl( fl(SZ + SC_k) - 2*dot(z,c_k) ), SZ/SC via numpy pairwise-8,
//   dot via sequential-K fma (BLAS order), first-min-wins tie break.
// R2: unrolled tap loop -> 256-VGPR cap -> scratch spill -> 12 GB HBM.
// R4: k2/k6 LDS-read bound -> s_load weights + big register tiles.
// R6 (REVERTED): per-thread-contiguous global access catastrophic.
// R7: global-cb loop L2-stream bound. R8: cb LDS chunks, 2pt/thr: VGPR=164,
//   421us, Occ 9% -> latency-bound.
// R9-R11: 1pt/thr: zr never left LDS (VGPR=52, k loop ds_read-bound 410us);
//   asm pins + launch_bounds minwaves cannot force promotion while the z
//   tile stays live in LDS.
// R12 (best k4, 316us): cb chunks clobber z tile -> zr leaves LDS. BUT
//   VGPR=64: RA put zr in AGPRs (its legacy model treats AGPR as free on the
//   unified file) -> v_accvgpr_read per fma use: VALU-busy 204us = 2.4x the
//   84us fma floor.
// R13 (REVERTED): s_load_dwordx16+lgkmcnt(0) per iter serialized SMEM,
//   376us, VGPR back to 52. Attributes can't fix an RA cost-model choice.
// R14 (this round): R12 structure + inline-asm v_fmac_f32 with "v"
//   constraints on ALL operands: every use demands an arch VGPR, so keeping
//   zr in AGPRs would cost a move per use -> RA's own model now picks arch
//   VGPRs. v_fmac D+=S0*S1 == fmaf exactly; chains interleaved, ascending
//   ci. Gate: VGPR_Count ~84-112, VALU-busy ~halves.
// Workspace (floats): h1/d1 @0 (25,690,112) | h2/zq @25,690,112 (12,845,056)
//   | z/d0 @38,535,168 (12,845,056) | cn @51,380,224 (512) | loss @51,380,736
// Out (floats): recon@0, z@3,211,264, z_q@16,056,320, loss@28,901,376,
//   idx@28,901,377 (200,704)
// ============================================================================

#define NB 4096

__device__ __forceinline__ float4 f4fma(float s, float4 w, float4 a) {
  a.x = fmaf(s, w.x, a.x); a.y = fmaf(s, w.y, a.y);
  a.z = fmaf(s, w.z, a.z); a.w = fmaf(s, w.w, a.w);
  return a;
}
__device__ __forceinline__ float4 f4relu(float4 a) {
  a.x = fmaxf(a.x, 0.f); a.y = fmaxf(a.y, 0.f);
  a.z = fmaxf(a.z, 0.f); a.w = fmaxf(a.w, 0.f);
  return a;
}
__device__ __forceinline__ float4 f4addrn(float4 a, float4 b) {
  a.x = __fadd_rn(a.x, b.x); a.y = __fadd_rn(a.y, b.y);
  a.z = __fadd_rn(a.z, b.z); a.w = __fadd_rn(a.w, b.w);
  return a;
}

// arch-VGPR fma: D = fma(S0,S1,D) with all operands forced to "v" class.
// Identical rounding to fmaf; blocks the RA from parking operands in AGPRs.
__device__ __forceinline__ void vfmac(float& d, float s0, float s1) {
  asm("v_fmac_f32 %0, %1, %2" : "+v"(d) : "v"(s0), "v"(s1));
}

// numpy pairwise-8 sum of squares over 64 contiguous values
__device__ __forceinline__ float np_sumsq64(const float* v) {
  float r[8];
#pragma unroll
  for (int j = 0; j < 8; ++j) r[j] = __fmul_rn(v[j], v[j]);
#pragma unroll
  for (int i = 8; i < 64; i += 8)
#pragma unroll
    for (int j = 0; j < 8; ++j) r[j] = __fadd_rn(r[j], __fmul_rn(v[i + j], v[i + j]));
  return __fadd_rn(__fadd_rn(__fadd_rn(r[0], r[1]), __fadd_rn(r[2], r[3])),
                   __fadd_rn(__fadd_rn(r[4], r[5]), __fadd_rn(r[6], r[7])));
}

// ---- K0: codebook norms (numpy-order) + zero loss accumulator --------------
__global__ __launch_bounds__(256) void k0_init(const float* __restrict__ cb,
                                               float* __restrict__ cn,
                                               float* __restrict__ loss) {
  int t = threadIdx.x;
  if (t == 0) *loss = 0.f;
  for (int k = t; k < 512; k += 256) cn[k] = np_sumsq64(&cb[k * 64]);
}

// ---- K1: conv1 4x4 s2 p1, 1->32, bias-after, ReLU. out h1 NHWC -------------
__global__ __launch_bounds__(256) void k1_conv1(const float* __restrict__ x,
                                                const float* __restrict__ w1,
                                                const float* __restrict__ b1,
                                                float* __restrict__ h1) {
  __shared__ float xs[784];
  __shared__ float wl[512];
  __shared__ float bs[32];
  int n = blockIdx.x, t = threadIdx.x;
  for (int j = t; j < 784; j += 256) xs[j] = x[n * 784 + j];
  for (int j = t; j < 512; j += 256) wl[j] = w1[j];
  if (t < 32) bs[t] = b1[t];
  __syncthreads();
  int c = t & 31, pg = t >> 5;
  for (int s = pg; s < 196; s += 8) {
    int oh = s / 14, ow = s % 14;
    float acc = 0.f;
#pragma unroll
    for (int kh = 0; kh < 4; ++kh) {
      int ih = 2 * oh - 1 + kh;
      if (ih < 0 || ih >= 28) continue;
#pragma unroll
      for (int kw = 0; kw < 4; ++kw) {
        int iw = 2 * ow - 1 + kw;
        if (iw < 0 || iw >= 28) continue;
        acc = fmaf(xs[ih * 28 + iw], wl[(kh * 4 + kw) * 32 + c], acc);
      }
    }
    acc = __fadd_rn(acc, bs[c]);
    h1[(n * 196 + s) * 32 + c] = fmaxf(acc, 0.f);
  }
}

// ---- K2: conv2 4x4 s2 p1, 32->64, bias-after, ReLU. NHWC -------------------
__global__ __launch_bounds__(256) void k2_conv2(const float* __restrict__ h1,
                                                const float* __restrict__ w2,
                                                const float* __restrict__ b2,
                                                float* __restrict__ h2) {
  __shared__ float4 xs4[2 * 2049];
  int nb = blockIdx.x, t = threadIdx.x;
  size_t n0 = (size_t)nb * 2;
  for (int j = t; j < 4098; j += 256) xs4[j] = make_float4(0.f, 0.f, 0.f, 0.f);
  __syncthreads();
  for (int j = t; j < 1568; j += 256) {
    int p = j >> 3, c4 = j & 7;
    int ihp = p / 14 + 1, iwp = p % 14 + 1;
    int chunk = (c4 * 16 + ihp) * 16 + (iwp & 1) * 8 + (iwp >> 1);
    xs4[chunk] = *(const float4*)(h1 + n0 * 6272 + p * 32 + c4 * 4);
    xs4[2049 + chunk] = *(const float4*)(h1 + (n0 + 1) * 6272 + p * 32 + c4 * 4);
  }
  __syncthreads();
  int l = t & 63;
  int co0 = __builtin_amdgcn_readfirstlane((t >> 6) * 16);
  int img = l >> 5, pt = l & 31;
  int oh0 = pt >> 3, ow = pt & 7;
  int imgoff = img * 2049;
  bool v0 = (ow < 7);
  bool v1 = (ow < 7) && (oh0 + 4 < 7);
  float4 A0[4], A1[4];
#pragma unroll
  for (int g = 0; g < 4; ++g) { A0[g] = make_float4(0.f, 0.f, 0.f, 0.f); A1[g] = A0[g]; }
#pragma unroll 1
  for (int kk = 0; kk < 16; ++kk) {
    int kh = kk >> 2, kw = kk & 3;
    int cc = 2 * ow + kw; if (cc > 15) cc = 15;
    int off = (cc & 1) * 8 + (cc >> 1);
    int rc0 = 2 * oh0 + kh;
    int rc1 = rc0 + 8; if (rc1 > 15) rc1 = 15;
    int b0 = imgoff + rc0 * 16 + off;
    int b1 = imgoff + rc1 * 16 + off;
    int wb = __builtin_amdgcn_readfirstlane(kk * 2048 + co0);
#pragma unroll 2
    for (int c4 = 0; c4 < 8; ++c4) {
      float4 x0 = xs4[b0 + c4 * 256];
      float4 x1 = xs4[b1 + c4 * 256];
      float xa0[4] = {x0.x, x0.y, x0.z, x0.w};
      float xa1[4] = {x1.x, x1.y, x1.z, x1.w};
      const float* wk = w2 + wb + c4 * 256;
#pragma unroll
      for (int j = 0; j < 4; ++j) {
#pragma unroll
        for (int g = 0; g < 4; ++g) {
          float4 wv4;
          wv4.x = wk[j * 64 + g * 4 + 0]; wv4.y = wk[j * 64 + g * 4 + 1];
          wv4.z = wk[j * 64 + g * 4 + 2]; wv4.w = wk[j * 64 + g * 4 + 3];
          A0[g] = f4fma(xa0[j], wv4, A0[g]);
          A1[g] = f4fma(xa1[j], wv4, A1[g]);
        }
      }
    }
  }
  float4 bias[4];
#pragma unroll
  for (int g = 0; g < 4; ++g) bias[g] = *(const float4*)&b2[co0 + g * 4];
  if (v0) {
    size_t ob = ((n0 + img) * 49 + oh0 * 7 + ow) * 64 + co0;
#pragma unroll
    for (int g = 0; g < 4; ++g)
      *(float4*)&h2[ob + g * 4] = f4relu(f4addrn(A0[g], bias[g]));
  }
  if (v1) {
    size_t ob = ((n0 + img) * 49 + (oh0 + 4) * 7 + ow) * 64 + co0;
#pragma unroll
    for (int g = 0; g < 4; ++g)
      *(float4*)&h2[ob + g * 4] = f4relu(f4addrn(A1[g], bias[g]));
  }
}

// ---- K_pw: 1x1 conv 64->64, bias-after (no act). NHWC ----------------------
__global__ __launch_bounds__(256) void k_pw(const float* __restrict__ xin,
                                            const float* __restrict__ w,     // [ci][co]
                                            const float* __restrict__ bias,
                                            float* __restrict__ yout) {
  __shared__ float tile[256 * 65];
  int t = threadIdx.x;
  long m0 = (long)blockIdx.x * 256;
  for (int j = t; j < 16384; j += 256) tile[(j >> 6) * 65 + (j & 63)] = xin[m0 * 64 + j];
  __syncthreads();
  float xr[64];
#pragma unroll
  for (int ci = 0; ci < 64; ++ci) xr[ci] = tile[t * 65 + ci];
  for (int g = 0; g < 4; ++g) {
    float4 z4 = make_float4(0.f, 0.f, 0.f, 0.f);
    float4 a0 = z4, a1 = z4, a2 = z4, a3 = z4;
#pragma unroll
    for (int ci = 0; ci < 64; ++ci) {
      float xv = xr[ci];
      const float* wr = &w[ci * 64 + g * 16];
      a0 = f4fma(xv, *(const float4*)&wr[0], a0);
      a1 = f4fma(xv, *(const float4*)&wr[4], a1);
      a2 = f4fma(xv, *(const float4*)&wr[8], a2);
      a3 = f4fma(xv, *(const float4*)&wr[12], a3);
    }
    a0 = f4addrn(a0, *(const float4*)&bias[g * 16 + 0]);
    a1 = f4addrn(a1, *(const float4*)&bias[g * 16 + 4]);
    a2 = f4addrn(a2, *(const float4*)&bias[g * 16 + 8]);
    a3 = f4addrn(a3, *(const float4*)&bias[g * 16 + 12]);
    float* dst = &tile[t * 65 + g * 16];
    dst[0] = a0.x; dst[1] = a0.y; dst[2] = a0.z; dst[3] = a0.w;
    dst[4] = a1.x; dst[5] = a1.y; dst[6] = a1.z; dst[7] = a1.w;
    dst[8] = a2.x; dst[9] = a2.y; dst[10] = a2.z; dst[11] = a2.w;
    dst[12] = a3.x; dst[13] = a3.y; dst[14] = a3.z; dst[15] = a3.w;
  }
  __syncthreads();
  for (int j = t; j < 16384; j += 256) yout[m0 * 64 + j] = tile[(j >> 6) * 65 + (j & 63)];
}

// ---- K4: VQ. 256 points/block (1/thread), cb in LDS chunks -----------------
// 784 blocks, 3 blk/CU (33.8KB LDS), ~12 waves/CU. cb chunks CLOBBER the z
// staging tile -> zr must leave LDS (R12 mechanism). Inner loop: broadcast
// ds_read_b128 of cb rows (wave-uniform, conflict-free) + inline-asm
// v_fmac_f32 all-"v" so zr lives in ARCH VGPRs, not AGPRs (R12: VGPR=64,
// accvgpr_read per fma = 2.4x VALU tax). k-unroll x2, chains interleaved,
// ascending ci, ascending-k first-min-wins: np-exact.
__global__ __launch_bounds__(256, 3) void k4_vq(const float* __restrict__ zin,
                                                const float* __restrict__ cb,
                                                const float* __restrict__ cn,
                                                float* __restrict__ zq_nhwc,
                                                float* __restrict__ outz,
                                                float* __restrict__ outzq,
                                                float* __restrict__ outidx,
                                                float* __restrict__ loss) {
  __shared__ float lds[8320];   // 128*65 tile  |  cbs[0..4096) + cns[4096..4608)
  __shared__ float red[4];
  int t = threadIdx.x;
  size_t m0 = (size_t)blockIdx.x * 256;
  float zr[64];

  // stage-in: two 128-row tiles, coalesced global -> LDS -> registers
#pragma unroll
  for (int S = 0; S < 2; ++S) {
    __syncthreads();
    const float* src = zin + (m0 + S * 128) * 64;
    for (int j4 = t; j4 < 2048; j4 += 256) {
      int row = j4 >> 4, col = (j4 & 15) * 4;
      *(float4*)&lds[row * 65 + col] = *(const float4*)(src + j4 * 4);
    }
    __syncthreads();
    if ((t >> 7) == S) {
      int r = t & 127;
#pragma unroll
      for (int ci = 0; ci < 64; ci += 4) {
        float4 v = *(float4*)&lds[r * 65 + ci];
        zr[ci] = v.x; zr[ci + 1] = v.y; zr[ci + 2] = v.z; zr[ci + 3] = v.w;
      }
    }
  }

  float sz = np_sumsq64(zr);
  float mind = 3.4e38f;
  int mi = 0;
#pragma unroll 1
  for (int ch = 0; ch < 8; ++ch) {
    __syncthreads();
    for (int j = t; j < 4096; j += 256) lds[j] = cb[ch * 4096 + j];   // clobbers z tile
    if (ch == 0)
      for (int j = t; j < 512; j += 256) lds[4096 + j] = cn[j];
    __syncthreads();
#pragma unroll 1
    for (int k = 0; k < 64; k += 2) {
      const float* r0 = &lds[k * 64];
      const float* r1 = r0 + 64;
      float d0 = 0.f, d1 = 0.f;
#pragma unroll
      for (int ci = 0; ci < 64; ci += 4) {
        float4 c0 = *(const float4*)(r0 + ci);
        float4 c1 = *(const float4*)(r1 + ci);
        vfmac(d0, zr[ci], c0.x);     vfmac(d1, zr[ci], c1.x);
        vfmac(d0, zr[ci + 1], c0.y); vfmac(d1, zr[ci + 1], c1.y);
        vfmac(d0, zr[ci + 2], c0.z); vfmac(d1, zr[ci + 2], c1.z);
        vfmac(d0, zr[ci + 3], c0.w); vfmac(d1, zr[ci + 3], c1.w);
      }
      float cn0 = lds[4096 + ch * 64 + k];
      float cn1 = lds[4096 + ch * 64 + k + 1];
      float q0 = __fsub_rn(__fadd_rn(sz, cn0), __fmul_rn(2.f, d0));
      float q1 = __fsub_rn(__fadd_rn(sz, cn1), __fmul_rn(2.f, d1));
      int kk = ch * 64 + k;
      if (q0 < mind) { mind = q0; mi = kk; }
      if (q1 < mind) { mind = q1; mi = kk + 1; }
    }
  }

  // idx + z NCHW scatter (zr still live)
  outidx[m0 + t] = (float)mi;
  {
    unsigned mA = (unsigned)(m0 + t);
    unsigned nA = mA / 49u, spA = mA % 49u;
    float* zo = outz + (size_t)nA * 3136 + spA;
#pragma unroll
    for (int ci = 0; ci < 64; ++ci) zo[ci * 49] = zr[ci];
  }

  float lsum = 0.f;
#pragma unroll
  for (int S = 0; S < 2; ++S) {
    __syncthreads();
    if ((t >> 7) == S) {
      int r = t & 127;
      unsigned mm = (unsigned)(m0 + S * 128 + r);
      unsigned nn = mm / 49u, ss = mm % 49u;
      float* qo = outzq + (size_t)nn * 3136 + ss;
      const float* qr = cb + (size_t)mi * 64;
#pragma unroll
      for (int ci = 0; ci < 64; ci += 4) {
        float4 q4 = *(const float4*)(qr + ci);
        *(float4*)&lds[r * 65 + ci] = q4;
        qo[(ci + 0) * 49] = q4.x; qo[(ci + 1) * 49] = q4.y;
        qo[(ci + 2) * 49] = q4.z; qo[(ci + 3) * 49] = q4.w;
        float e0 = q4.x - zr[ci], e1 = q4.y - zr[ci + 1];
        float e2 = q4.z - zr[ci + 2], e3 = q4.w - zr[ci + 3];
        lsum = fmaf(e0, e0, lsum); lsum = fmaf(e1, e1, lsum);
        lsum = fmaf(e2, e2, lsum); lsum = fmaf(e3, e3, lsum);
      }
    }
    __syncthreads();
    float* dstg = zq_nhwc + (m0 + S * 128) * 64;
    for (int j4 = t; j4 < 2048; j4 += 256) {
      int row = j4 >> 4, col = (j4 & 15) * 4;
      *(float4*)(dstg + j4 * 4) = *(float4*)&lds[row * 65 + col];
    }
  }
#pragma unroll
  for (int off = 32; off > 0; off >>= 1) lsum += __shfl_down(lsum, off);
  int wid = t >> 6, lane = t & 63;
  if (lane == 0) red[wid] = lsum;
  __syncthreads();
  if (t == 0) atomicAdd(loss, red[0] + red[1] + red[2] + red[3]);
}

// ---- K4b: finalize loss ----------------------------------------------------
__global__ __launch_bounds__(64) void k_lossfin(const float* __restrict__ loss,
                                                float* __restrict__ out) {
  if (threadIdx.x == 0) out[0] = loss[0] * (1.25f / 12845056.f);
}

// ---- K6: deconv1 4x4 s2 p2 (lhs_dilation), 64->32, ReLU. NHWC --------------
__global__ __launch_bounds__(256) void k6_deconv1(const float* __restrict__ d0,
                                                  const float* __restrict__ dw1,
                                                  const float* __restrict__ db1,
                                                  float* __restrict__ d1) {
  __shared__ float4 xs4[2 * 1297];
  int nb = blockIdx.x, t = threadIdx.x;
  size_t n0 = (size_t)nb * 2;
  for (int j = t; j < 2594; j += 256) xs4[j] = make_float4(0.f, 0.f, 0.f, 0.f);
  __syncthreads();
  for (int j = t; j < 784; j += 256) {
    int p = j >> 4, c4 = j & 15;
    int chunk = c4 * 81 + (p / 7 + 1) * 9 + (p % 7 + 1);
    xs4[chunk] = *(const float4*)(d0 + n0 * 3136 + p * 64 + c4 * 4);
    xs4[1297 + chunk] = *(const float4*)(d0 + (n0 + 1) * 3136 + p * 64 + c4 * 4);
  }
  __syncthreads();
  int l = t & 63;
  int ph = __builtin_amdgcn_readfirstlane(t >> 6);
  int ra = ph >> 1, rb = ph & 1;
  int img = l >> 5, pt = l & 31;
  bool v1 = (pt + 32 < 49);
  int p1 = v1 ? pt + 32 : 48;
  int mh0 = pt / 7, mw0 = pt % 7;
  int mh1 = p1 / 7, mw1 = p1 % 7;
  int imgoff = img * 1297;
  float4 A0[8], A1[8];
#pragma unroll
  for (int g = 0; g < 8; ++g) { A0[g] = make_float4(0.f, 0.f, 0.f, 0.f); A1[g] = A0[g]; }
#pragma unroll 1
  for (int tap = 0; tap < 4; ++tap) {
    int th = tap >> 1, tw = tap & 1;
    int kh = 2 * th + ra, kw = 2 * tw + rb;
    int b0 = imgoff + (mh0 + th + ra) * 9 + (mw0 + tw + rb);
    int b1 = imgoff + (mh1 + th + ra) * 9 + (mw1 + tw + rb);
    int wb = __builtin_amdgcn_readfirstlane((kh * 4 + kw) * 2048);
#pragma unroll 1
    for (int c4 = 0; c4 < 16; ++c4) {
      float4 x0 = xs4[b0 + c4 * 81];
      float4 x1 = xs4[b1 + c4 * 81];
      float xa0[4] = {x0.x, x0.y, x0.z, x0.w};
      float xa1[4] = {x1.x, x1.y, x1.z, x1.w};
      const float* wk = dw1 + wb + c4 * 128;
#pragma unroll
      for (int j = 0; j < 4; ++j) {
#pragma unroll
        for (int g = 0; g < 8; ++g) {
          float4 wv4;
          wv4.x = wk[j * 32 + g * 4 + 0]; wv4.y = wk[j * 32 + g * 4 + 1];
          wv4.z = wk[j * 32 + g * 4 + 2]; wv4.w = wk[j * 32 + g * 4 + 3];
          A0[g] = f4fma(xa0[j], wv4, A0[g]);
          A1[g] = f4fma(xa1[j], wv4, A1[g]);
        }
      }
    }
  }
  int oh0 = 2 * mh0 + ra, ow0 = 2 * mw0 + rb;
  size_t ob0 = ((n0 + img) * 196 + (size_t)(oh0 * 14 + ow0)) * 32;
#pragma unroll
  for (int g = 0; g < 8; ++g) {
    float4 bg = *(const float4*)&db1[g * 4];
    *(float4*)&d1[ob0 + g * 4] = f4relu(f4addrn(A0[g], bg));
  }
  if (v1) {
    int oh1 = 2 * mh1 + ra, ow1 = 2 * mw1 + rb;
    size_t ob1 = ((n0 + img) * 196 + (size_t)(oh1 * 14 + ow1)) * 32;
#pragma unroll
    for (int g = 0; g < 8; ++g) {
      float4 bg = *(const float4*)&db1[g * 4];
      *(float4*)&d1[ob1 + g * 4] = f4relu(f4addrn(A1[g], bg));
    }
  }
}

// ---- K7: deconv2 4x4 s2 p2, 32->1, sigmoid -> recon NCHW -------------------
__global__ __launch_bounds__(256) void k7_deconv2(const float* __restrict__ d1,
                                                  const float* __restrict__ dw2,
                                                  const float* __restrict__ db2,
                                                  float* __restrict__ recon) {
  __shared__ float xs[196 * 36];
  __shared__ float wl[512];
  int n = blockIdx.x, t = threadIdx.x;
  for (int j = t; j < 6272; j += 256) xs[(j >> 5) * 36 + (j & 31)] = d1[(size_t)n * 6272 + j];
  for (int j = t; j < 512; j += 256) wl[j] = dw2[j];
  __syncthreads();
  float bias = db2[0];
  for (int j = t; j < 392; j += 256) {
    int ra = j / 196, rem = j % 196;
    int mh = rem / 14, mw = rem % 14;
    float acc0 = bias, acc1 = bias;
    bool vm = (mw >= 1), vp = (mw + 1 < 14);
#pragma unroll
    for (int th = 0; th < 2; ++th) {
      int ih = mh + th - 1 + ra;
      if (ih < 0 || ih >= 14) continue;
      int kh = 2 * th + ra;
#pragma unroll
      for (int ci = 0; ci < 32; ci += 4) {
        float4 z4 = make_float4(0.f, 0.f, 0.f, 0.f);
        float4 xm = vm ? *(float4*)&xs[(ih * 14 + mw - 1) * 36 + ci] : z4;
        float4 x0 = *(float4*)&xs[(ih * 14 + mw) * 36 + ci];
        float4 xp = vp ? *(float4*)&xs[(ih * 14 + mw + 1) * 36 + ci] : z4;
        float4 wk0 = *(float4*)&wl[(kh * 4 + 0) * 32 + ci];
        float4 wk1 = *(float4*)&wl[(kh * 4 + 1) * 32 + ci];
        float4 wk2 = *(float4*)&wl[(kh * 4 + 2) * 32 + ci];
        float4 wk3 = *(float4*)&wl[(kh * 4 + 3) * 32 + ci];
        acc0 = fmaf(xm.x, wk0.x, acc0); acc0 = fmaf(xm.y, wk0.y, acc0);
        acc0 = fmaf(xm.z, wk0.z, acc0); acc0 = fmaf(xm.w, wk0.w, acc0);
        acc0 = fmaf(x0.x, wk2.x, acc0); acc0 = fmaf(x0.y, wk2.y, acc0);
        acc0 = fmaf(x0.z, wk2.z, acc0); acc0 = fmaf(x0.w, wk2.w, acc0);
        acc1 = fmaf(x0.x, wk1.x, acc1); acc1 = fmaf(x0.y, wk1.y, acc1);
        acc1 = fmaf(x0.z, wk1.z, acc1); acc1 = fmaf(x0.w, wk1.w, acc1);
        acc1 = fmaf(xp.x, wk3.x, acc1); acc1 = fmaf(xp.y, wk3.y, acc1);
        acc1 = fmaf(xp.z, wk3.z, acc1); acc1 = fmaf(xp.w, wk3.w, acc1);
      }
    }
    float r0 = 1.f / (1.f + __expf(-acc0));
    float r1 = 1.f / (1.f + __expf(-acc1));
    int oh = 2 * mh + ra;
    *(float2*)&recon[(size_t)n * 784 + oh * 28 + 2 * mw] = make_float2(r0, r1);
  }
}

extern "C" void kernel_launch(void* const* d_in, const int* in_sizes, int n_in,
                              void* d_out, int out_size, void* d_ws, size_t ws_size,
                              hipStream_t stream) {
  const float* x   = (const float*)d_in[0];
  const float* w1  = (const float*)d_in[1];
  const float* b1  = (const float*)d_in[2];
  const float* w2  = (const float*)d_in[3];
  const float* b2  = (const float*)d_in[4];
  const float* w3  = (const float*)d_in[5];
  const float* b3  = (const float*)d_in[6];
  const float* cb  = (const float*)d_in[7];
  const float* dw0 = (const float*)d_in[8];
  const float* db0 = (const float*)d_in[9];
  const float* dw1 = (const float*)d_in[10];
  const float* db1 = (const float*)d_in[11];
  const float* dw2 = (const float*)d_in[12];
  const float* db2 = (const float*)d_in[13];
  float* out = (float*)d_out;
  float* ws  = (float*)d_ws;

  float* h1   = ws;                 // 25,690,112 (reused as d1)
  float* h2   = ws + 25690112;      // 12,845,056 (reused as zq_nhwc)
  float* zb   = ws + 38535168;      // 12,845,056 z_nhwc (reused as d0)
  float* cn   = ws + 51380224;      // 512
  float* loss = ws + 51380736;      // 1

  float* recon   = out;
  float* zout    = out + 3211264;
  float* zqout   = out + 16056320;
  float* lossout = out + 28901376;
  float* idxout  = out + 28901377;

  k0_init<<<1, 256, 0, stream>>>(cb, cn, loss);
  k1_conv1<<<NB, 256, 0, stream>>>(x, w1, b1, h1);
  k2_conv2<<<NB / 2, 256, 0, stream>>>(h1, w2, b2, h2);
  k_pw<<<784, 256, 0, stream>>>(h2, w3, b3, zb);                 // z = h2 @ w3 + b3
  k4_vq<<<784, 256, 0, stream>>>(zb, cb, cn, h2, zout, zqout, idxout, loss);
  k_lossfin<<<1, 64, 0, stream>>>(loss, lossout);
  k_pw<<<784, 256, 0, stream>>>(h2, dw0, db0, zb);               // d0 = zq @ dw0 + db0
  k6_deconv1<<<NB / 2, 256, 0, stream>>>(zb, dw1, db1, h1);
  k7_deconv2<<<NB, 256, 0, stream>>>(h1, dw2, db2, recon);
}

// Round 8
// 1101.955 us; speedup vs baseline: 1.0581x; 1.0122x over previous
//
#include <hip/hip_runtime.h>

// ============================================================================
// VQ-VAE forward, MI355X fp32. Internal layout NHWC; outputs NCHW.
// B=4096. x(4096,1,28,28) -> h1(4096,14,14,32) -> h2(4096,7,7,64)
//   -> z -> VQ(512 codes, D=64) -> d0 -> d1(4096,14,14,32) -> recon.
// VQ argmin reproduces np fp32 semantics exactly:
//   dist = fl( fl(SZ + SC_k) - 2*dot(z,c_k) ), SZ/SC via numpy pairwise-8,
//   dot via sequential-K fma (BLAS order), first-min-wins tie break.
// R2: unrolled tap loop -> 256-VGPR cap -> scratch spill -> 12 GB HBM.
// R4: k2/k6 LDS-read bound -> s_load weights + big register tiles.
// R6 (REVERTED): per-thread-contiguous global access catastrophic.
// R7: global-cb loop L2-stream bound.
// R8: cb LDS chunks (16KB x8), 256 thr x 2pt: VGPR=164 (ARCH-resident zr!),
//   421us -- but 392 blocks = 1.53 blk/CU, Occ 9%, grid-limited latency.
// R9-R11: 1pt/thr reshapes: zr never promoted (VGPR=52, LDS-bound 410us).
// R12: chunk-clobber 1pt/thr: zr -> AGPRs (VGPR=64), accvgpr_read per fma,
//   VALU-busy 205us vs 92us floor; 316us.
// R13-R15 (all dead): SGPR stream serialized SMEM (376us); "v"-constraint
//   fmac didn't move allocation; "a"-sourcing v_fmac REJECTED by gfx950
//   assembler (VOP2 cannot encode AGPR src). Conclusion: 1pt/thread WILL be
//   AGPR-parked and taxed; only the 2pt/thread shape promotes to arch VGPRs.
// R16 (this round): R8 structure, 128-thread blocks: 2pt/thr x 128thr = 256
//   pts/block, 784 blocks -> ~6.1 waves/CU (2.1x R8), LDS 33.3KB (4 blk/CU
//   cap), __launch_bounds__(128,2) -> 256-VGPR budget. Inner loop = R8's
//   4-chain np-exact code, plain HIP. Gate: VGPR ~160-200, k4 ~210-260us.
// Workspace (floats): h1/d1 @0 (25,690,112) | h2/zq @25,690,112 (12,845,056)
//   | z/d0 @38,535,168 (12,845,056) | cn @51,380,224 (512) | loss @51,380,736
// Out (floats): recon@0, z@3,211,264, z_q@16,056,320, loss@28,901,376,
//   idx@28,901,377 (200,704)
// ============================================================================

#define NB 4096

__device__ __forceinline__ float4 f4fma(float s, float4 w, float4 a) {
  a.x = fmaf(s, w.x, a.x); a.y = fmaf(s, w.y, a.y);
  a.z = fmaf(s, w.z, a.z); a.w = fmaf(s, w.w, a.w);
  return a;
}
__device__ __forceinline__ float4 f4relu(float4 a) {
  a.x = fmaxf(a.x, 0.f); a.y = fmaxf(a.y, 0.f);
  a.z = fmaxf(a.z, 0.f); a.w = fmaxf(a.w, 0.f);
  return a;
}
__device__ __forceinline__ float4 f4addrn(float4 a, float4 b) {
  a.x = __fadd_rn(a.x, b.x); a.y = __fadd_rn(a.y, b.y);
  a.z = __fadd_rn(a.z, b.z); a.w = __fadd_rn(a.w, b.w);
  return a;
}

// numpy pairwise-8 sum of squares over 64 contiguous values
__device__ __forceinline__ float np_sumsq64(const float* v) {
  float r[8];
#pragma unroll
  for (int j = 0; j < 8; ++j) r[j] = __fmul_rn(v[j], v[j]);
#pragma unroll
  for (int i = 8; i < 64; i += 8)
#pragma unroll
    for (int j = 0; j < 8; ++j) r[j] = __fadd_rn(r[j], __fmul_rn(v[i + j], v[i + j]));
  return __fadd_rn(__fadd_rn(__fadd_rn(r[0], r[1]), __fadd_rn(r[2], r[3])),
                   __fadd_rn(__fadd_rn(r[4], r[5]), __fadd_rn(r[6], r[7])));
}

// ---- K0: codebook norms (numpy-order) + zero loss accumulator --------------
__global__ __launch_bounds__(256) void k0_init(const float* __restrict__ cb,
                                               float* __restrict__ cn,
                                               float* __restrict__ loss) {
  int t = threadIdx.x;
  if (t == 0) *loss = 0.f;
  for (int k = t; k < 512; k += 256) cn[k] = np_sumsq64(&cb[k * 64]);
}

// ---- K1: conv1 4x4 s2 p1, 1->32, bias-after, ReLU. out h1 NHWC -------------
__global__ __launch_bounds__(256) void k1_conv1(const float* __restrict__ x,
                                                const float* __restrict__ w1,
                                                const float* __restrict__ b1,
                                                float* __restrict__ h1) {
  __shared__ float xs[784];
  __shared__ float wl[512];
  __shared__ float bs[32];
  int n = blockIdx.x, t = threadIdx.x;
  for (int j = t; j < 784; j += 256) xs[j] = x[n * 784 + j];
  for (int j = t; j < 512; j += 256) wl[j] = w1[j];
  if (t < 32) bs[t] = b1[t];
  __syncthreads();
  int c = t & 31, pg = t >> 5;
  for (int s = pg; s < 196; s += 8) {
    int oh = s / 14, ow = s % 14;
    float acc = 0.f;
#pragma unroll
    for (int kh = 0; kh < 4; ++kh) {
      int ih = 2 * oh - 1 + kh;
      if (ih < 0 || ih >= 28) continue;
#pragma unroll
      for (int kw = 0; kw < 4; ++kw) {
        int iw = 2 * ow - 1 + kw;
        if (iw < 0 || iw >= 28) continue;
        acc = fmaf(xs[ih * 28 + iw], wl[(kh * 4 + kw) * 32 + c], acc);
      }
    }
    acc = __fadd_rn(acc, bs[c]);
    h1[(n * 196 + s) * 32 + c] = fmaxf(acc, 0.f);
  }
}

// ---- K2: conv2 4x4 s2 p1, 32->64, bias-after, ReLU. NHWC -------------------
__global__ __launch_bounds__(256) void k2_conv2(const float* __restrict__ h1,
                                                const float* __restrict__ w2,
                                                const float* __restrict__ b2,
                                                float* __restrict__ h2) {
  __shared__ float4 xs4[2 * 2049];
  int nb = blockIdx.x, t = threadIdx.x;
  size_t n0 = (size_t)nb * 2;
  for (int j = t; j < 4098; j += 256) xs4[j] = make_float4(0.f, 0.f, 0.f, 0.f);
  __syncthreads();
  for (int j = t; j < 1568; j += 256) {
    int p = j >> 3, c4 = j & 7;
    int ihp = p / 14 + 1, iwp = p % 14 + 1;
    int chunk = (c4 * 16 + ihp) * 16 + (iwp & 1) * 8 + (iwp >> 1);
    xs4[chunk] = *(const float4*)(h1 + n0 * 6272 + p * 32 + c4 * 4);
    xs4[2049 + chunk] = *(const float4*)(h1 + (n0 + 1) * 6272 + p * 32 + c4 * 4);
  }
  __syncthreads();
  int l = t & 63;
  int co0 = __builtin_amdgcn_readfirstlane((t >> 6) * 16);
  int img = l >> 5, pt = l & 31;
  int oh0 = pt >> 3, ow = pt & 7;
  int imgoff = img * 2049;
  bool v0 = (ow < 7);
  bool v1 = (ow < 7) && (oh0 + 4 < 7);
  float4 A0[4], A1[4];
#pragma unroll
  for (int g = 0; g < 4; ++g) { A0[g] = make_float4(0.f, 0.f, 0.f, 0.f); A1[g] = A0[g]; }
#pragma unroll 1
  for (int kk = 0; kk < 16; ++kk) {
    int kh = kk >> 2, kw = kk & 3;
    int cc = 2 * ow + kw; if (cc > 15) cc = 15;
    int off = (cc & 1) * 8 + (cc >> 1);
    int rc0 = 2 * oh0 + kh;
    int rc1 = rc0 + 8; if (rc1 > 15) rc1 = 15;
    int b0 = imgoff + rc0 * 16 + off;
    int b1 = imgoff + rc1 * 16 + off;
    int wb = __builtin_amdgcn_readfirstlane(kk * 2048 + co0);
#pragma unroll 2
    for (int c4 = 0; c4 < 8; ++c4) {
      float4 x0 = xs4[b0 + c4 * 256];
      float4 x1 = xs4[b1 + c4 * 256];
      float xa0[4] = {x0.x, x0.y, x0.z, x0.w};
      float xa1[4] = {x1.x, x1.y, x1.z, x1.w};
      const float* wk = w2 + wb + c4 * 256;
#pragma unroll
      for (int j = 0; j < 4; ++j) {
#pragma unroll
        for (int g = 0; g < 4; ++g) {
          float4 wv4;
          wv4.x = wk[j * 64 + g * 4 + 0]; wv4.y = wk[j * 64 + g * 4 + 1];
          wv4.z = wk[j * 64 + g * 4 + 2]; wv4.w = wk[j * 64 + g * 4 + 3];
          A0[g] = f4fma(xa0[j], wv4, A0[g]);
          A1[g] = f4fma(xa1[j], wv4, A1[g]);
        }
      }
    }
  }
  float4 bias[4];
#pragma unroll
  for (int g = 0; g < 4; ++g) bias[g] = *(const float4*)&b2[co0 + g * 4];
  if (v0) {
    size_t ob = ((n0 + img) * 49 + oh0 * 7 + ow) * 64 + co0;
#pragma unroll
    for (int g = 0; g < 4; ++g)
      *(float4*)&h2[ob + g * 4] = f4relu(f4addrn(A0[g], bias[g]));
  }
  if (v1) {
    size_t ob = ((n0 + img) * 49 + (oh0 + 4) * 7 + ow) * 64 + co0;
#pragma unroll
    for (int g = 0; g < 4; ++g)
      *(float4*)&h2[ob + g * 4] = f4relu(f4addrn(A1[g], bias[g]));
  }
}

// ---- K_pw: 1x1 conv 64->64, bias-after (no act). NHWC ----------------------
__global__ __launch_bounds__(256) void k_pw(const float* __restrict__ xin,
                                            const float* __restrict__ w,     // [ci][co]
                                            const float* __restrict__ bias,
                                            float* __restrict__ yout) {
  __shared__ float tile[256 * 65];
  int t = threadIdx.x;
  long m0 = (long)blockIdx.x * 256;
  for (int j = t; j < 16384; j += 256) tile[(j >> 6) * 65 + (j & 63)] = xin[m0 * 64 + j];
  __syncthreads();
  float xr[64];
#pragma unroll
  for (int ci = 0; ci < 64; ++ci) xr[ci] = tile[t * 65 + ci];
  for (int g = 0; g < 4; ++g) {
    float4 z4 = make_float4(0.f, 0.f, 0.f, 0.f);
    float4 a0 = z4, a1 = z4, a2 = z4, a3 = z4;
#pragma unroll
    for (int ci = 0; ci < 64; ++ci) {
      float xv = xr[ci];
      const float* wr = &w[ci * 64 + g * 16];
      a0 = f4fma(xv, *(const float4*)&wr[0], a0);
      a1 = f4fma(xv, *(const float4*)&wr[4], a1);
      a2 = f4fma(xv, *(const float4*)&wr[8], a2);
      a3 = f4fma(xv, *(const float4*)&wr[12], a3);
    }
    a0 = f4addrn(a0, *(const float4*)&bias[g * 16 + 0]);
    a1 = f4addrn(a1, *(const float4*)&bias[g * 16 + 4]);
    a2 = f4addrn(a2, *(const float4*)&bias[g * 16 + 8]);
    a3 = f4addrn(a3, *(const float4*)&bias[g * 16 + 12]);
    float* dst = &tile[t * 65 + g * 16];
    dst[0] = a0.x; dst[1] = a0.y; dst[2] = a0.z; dst[3] = a0.w;
    dst[4] = a1.x; dst[5] = a1.y; dst[6] = a1.z; dst[7] = a1.w;
    dst[8] = a2.x; dst[9] = a2.y; dst[10] = a2.z; dst[11] = a2.w;
    dst[12] = a3.x; dst[13] = a3.y; dst[14] = a3.z; dst[15] = a3.w;
  }
  __syncthreads();
  for (int j = t; j < 16384; j += 256) yout[m0 * 64 + j] = tile[(j >> 6) * 65 + (j & 63)];
}

// ---- K4: VQ. 128 threads, 2 points/thread = 256 pts/block, 784 blocks ------
// R8's arch-VGPR-promoting shape (zrA+zrB = 128 floats forces arch VGPRs,
// proven VGPR=164) with 2.1x R8's occupancy (6.1 waves/CU). cb in LDS 16KB
// chunks clobbering the z tile; broadcast ds_read conflict-free. 4 chains.
// np-exact per-code fma order and k-ascending first-min-wins compares.
__global__ __launch_bounds__(128, 2) void k4_vq(const float* __restrict__ zin,
                                                const float* __restrict__ cb,
                                                const float* __restrict__ cn,
                                                float* __restrict__ zq_nhwc,
                                                float* __restrict__ outz,
                                                float* __restrict__ outzq,
                                                float* __restrict__ outidx,
                                                float* __restrict__ loss) {
  __shared__ float lds[8320];   // 128*65 tile  |  cbs[0..4096) + cns[4096..4608)
  __shared__ float red[2];
  int t = threadIdx.x;          // 0..127
  size_t m0 = (size_t)blockIdx.x * 256;
  float zrA[64], zrB[64];

#define K4_STAGE_IN(S, ZR)                                                    \
  {                                                                           \
    __syncthreads();                                                          \
    const float* src = zin + (m0 + (S) * 128) * 64;                           \
    for (int j4 = t; j4 < 2048; j4 += 128) {                                  \
      int row = j4 >> 4, col = (j4 & 15) * 4;                                 \
      *(float4*)&lds[row * 65 + col] = *(const float4*)(src + j4 * 4);        \
    }                                                                         \
    __syncthreads();                                                          \
    _Pragma("unroll")                                                         \
    for (int ci = 0; ci < 64; ci += 4) {                                      \
      float4 v = *(float4*)&lds[t * 65 + ci];                                 \
      ZR[ci] = v.x; ZR[ci + 1] = v.y; ZR[ci + 2] = v.z; ZR[ci + 3] = v.w;     \
    }                                                                         \
  }

  K4_STAGE_IN(0, zrA)
  K4_STAGE_IN(1, zrB)

  float szA = np_sumsq64(zrA), szB = np_sumsq64(zrB);
  float minA = 3.4e38f, minB = 3.4e38f;
  int miA = 0, miB = 0;
#pragma unroll 1
  for (int ch = 0; ch < 8; ++ch) {
    __syncthreads();
    for (int j = t; j < 4096; j += 128) lds[j] = cb[ch * 4096 + j];   // clobbers z tile
    if (ch == 0)
      for (int j = t; j < 512; j += 128) lds[4096 + j] = cn[j];
    __syncthreads();
#pragma unroll 1
    for (int k = 0; k < 64; k += 2) {
      const float* r0 = &lds[k * 64];
      const float* r1 = r0 + 64;
      float dA0 = 0.f, dA1 = 0.f, dB0 = 0.f, dB1 = 0.f;
#pragma unroll
      for (int ci = 0; ci < 64; ci += 4) {
        float4 c0 = *(const float4*)(r0 + ci);
        float4 c1 = *(const float4*)(r1 + ci);
        dA0 = fmaf(zrA[ci], c0.x, dA0); dA0 = fmaf(zrA[ci + 1], c0.y, dA0);
        dA0 = fmaf(zrA[ci + 2], c0.z, dA0); dA0 = fmaf(zrA[ci + 3], c0.w, dA0);
        dB0 = fmaf(zrB[ci], c0.x, dB0); dB0 = fmaf(zrB[ci + 1], c0.y, dB0);
        dB0 = fmaf(zrB[ci + 2], c0.z, dB0); dB0 = fmaf(zrB[ci + 3], c0.w, dB0);
        dA1 = fmaf(zrA[ci], c1.x, dA1); dA1 = fmaf(zrA[ci + 1], c1.y, dA1);
        dA1 = fmaf(zrA[ci + 2], c1.z, dA1); dA1 = fmaf(zrA[ci + 3], c1.w, dA1);
        dB1 = fmaf(zrB[ci], c1.x, dB1); dB1 = fmaf(zrB[ci + 1], c1.y, dB1);
        dB1 = fmaf(zrB[ci + 2], c1.z, dB1); dB1 = fmaf(zrB[ci + 3], c1.w, dB1);
      }
      float cn0 = lds[4096 + ch * 64 + k];
      float cn1 = lds[4096 + ch * 64 + k + 1];
      float qA0 = __fsub_rn(__fadd_rn(szA, cn0), __fmul_rn(2.f, dA0));
      float qA1 = __fsub_rn(__fadd_rn(szA, cn1), __fmul_rn(2.f, dA1));
      float qB0 = __fsub_rn(__fadd_rn(szB, cn0), __fmul_rn(2.f, dB0));
      float qB1 = __fsub_rn(__fadd_rn(szB, cn1), __fmul_rn(2.f, dB1));
      int kk = ch * 64 + k;
      if (qA0 < minA) { minA = qA0; miA = kk; }
      if (qA1 < minA) { minA = qA1; miA = kk + 1; }
      if (qB0 < minB) { minB = qB0; miB = kk; }
      if (qB1 < minB) { minB = qB1; miB = kk + 1; }
    }
  }

  // idx + z NCHW scatter (zr still live)
  outidx[m0 + t] = (float)miA;
  outidx[m0 + 128 + t] = (float)miB;
  {
    unsigned mA = (unsigned)(m0 + t), mB = (unsigned)(m0 + 128 + t);
    unsigned nA = mA / 49u, spA = mA % 49u;
    unsigned nB = mB / 49u, spB = mB % 49u;
    float* zoA = outz + (size_t)nA * 3136 + spA;
    float* zoB = outz + (size_t)nB * 3136 + spB;
#pragma unroll
    for (int ci = 0; ci < 64; ++ci) { zoA[ci * 49] = zrA[ci]; zoB[ci * 49] = zrB[ci]; }
  }

  float lsum = 0.f;
#define K4_STAGE_OUT(S, ZR, MI)                                               \
  {                                                                           \
    __syncthreads();                                                          \
    {                                                                         \
      unsigned mm = (unsigned)(m0 + (S) * 128 + t);                           \
      unsigned nn = mm / 49u, ss = mm % 49u;                                  \
      float* qo = outzq + (size_t)nn * 3136 + ss;                             \
      const float* qr = cb + (size_t)(MI) * 64;                               \
      _Pragma("unroll")                                                       \
      for (int ci = 0; ci < 64; ci += 4) {                                    \
        float4 q4 = *(const float4*)(qr + ci);                                \
        *(float4*)&lds[t * 65 + ci] = q4;                                     \
        qo[(ci + 0) * 49] = q4.x; qo[(ci + 1) * 49] = q4.y;                   \
        qo[(ci + 2) * 49] = q4.z; qo[(ci + 3) * 49] = q4.w;                   \
        float e0 = q4.x - ZR[ci], e1 = q4.y - ZR[ci + 1];                     \
        float e2 = q4.z - ZR[ci + 2], e3 = q4.w - ZR[ci + 3];                 \
        lsum = fmaf(e0, e0, lsum); lsum = fmaf(e1, e1, lsum);                 \
        lsum = fmaf(e2, e2, lsum); lsum = fmaf(e3, e3, lsum);                 \
      }                                                                       \
    }                                                                         \
    __syncthreads();                                                          \
    float* dstg = zq_nhwc + (m0 + (S) * 128) * 64;                            \
    for (int j4 = t; j4 < 2048; j4 += 128) {                                  \
      int row = j4 >> 4, col = (j4 & 15) * 4;                                 \
      *(float4*)(dstg + j4 * 4) = *(float4*)&lds[row * 65 + col];             \
    }                                                                         \
  }
  K4_STAGE_OUT(0, zrA, miA)
  K4_STAGE_OUT(1, zrB, miB)
#undef K4_STAGE_IN
#undef K4_STAGE_OUT
#pragma unroll
  for (int off = 32; off > 0; off >>= 1) lsum += __shfl_down(lsum, off);
  int wid = t >> 6, lane = t & 63;
  if (lane == 0) red[wid] = lsum;
  __syncthreads();
  if (t == 0) atomicAdd(loss, red[0] + red[1]);
}

// ---- K4b: finalize loss ----------------------------------------------------
__global__ __launch_bounds__(64) void k_lossfin(const float* __restrict__ loss,
                                                float* __restrict__ out) {
  if (threadIdx.x == 0) out[0] = loss[0] * (1.25f / 12845056.f);
}

// ---- K6: deconv1 4x4 s2 p2 (lhs_dilation), 64->32, ReLU. NHWC --------------
__global__ __launch_bounds__(256) void k6_deconv1(const float* __restrict__ d0,
                                                  const float* __restrict__ dw1,
                                                  const float* __restrict__ db1,
                                                  float* __restrict__ d1) {
  __shared__ float4 xs4[2 * 1297];
  int nb = blockIdx.x, t = threadIdx.x;
  size_t n0 = (size_t)nb * 2;
  for (int j = t; j < 2594; j += 256) xs4[j] = make_float4(0.f, 0.f, 0.f, 0.f);
  __syncthreads();
  for (int j = t; j < 784; j += 256) {
    int p = j >> 4, c4 = j & 15;
    int chunk = c4 * 81 + (p / 7 + 1) * 9 + (p % 7 + 1);
    xs4[chunk] = *(const float4*)(d0 + n0 * 3136 + p * 64 + c4 * 4);
    xs4[1297 + chunk] = *(const float4*)(d0 + (n0 + 1) * 3136 + p * 64 + c4 * 4);
  }
  __syncthreads();
  int l = t & 63;
  int ph = __builtin_amdgcn_readfirstlane(t >> 6);
  int ra = ph >> 1, rb = ph & 1;
  int img = l >> 5, pt = l & 31;
  bool v1 = (pt + 32 < 49);
  int p1 = v1 ? pt + 32 : 48;
  int mh0 = pt / 7, mw0 = pt % 7;
  int mh1 = p1 / 7, mw1 = p1 % 7;
  int imgoff = img * 1297;
  float4 A0[8], A1[8];
#pragma unroll
  for (int g = 0; g < 8; ++g) { A0[g] = make_float4(0.f, 0.f, 0.f, 0.f); A1[g] = A0[g]; }
#pragma unroll 1
  for (int tap = 0; tap < 4; ++tap) {
    int th = tap >> 1, tw = tap & 1;
    int kh = 2 * th + ra, kw = 2 * tw + rb;
    int b0 = imgoff + (mh0 + th + ra) * 9 + (mw0 + tw + rb);
    int b1 = imgoff + (mh1 + th + ra) * 9 + (mw1 + tw + rb);
    int wb = __builtin_amdgcn_readfirstlane((kh * 4 + kw) * 2048);
#pragma unroll 1
    for (int c4 = 0; c4 < 16; ++c4) {
      float4 x0 = xs4[b0 + c4 * 81];
      float4 x1 = xs4[b1 + c4 * 81];
      float xa0[4] = {x0.x, x0.y, x0.z, x0.w};
      float xa1[4] = {x1.x, x1.y, x1.z, x1.w};
      const float* wk = dw1 + wb + c4 * 128;
#pragma unroll
      for (int j = 0; j < 4; ++j) {
#pragma unroll
        for (int g = 0; g < 8; ++g) {
          float4 wv4;
          wv4.x = wk[j * 32 + g * 4 + 0]; wv4.y = wk[j * 32 + g * 4 + 1];
          wv4.z = wk[j * 32 + g * 4 + 2]; wv4.w = wk[j * 32 + g * 4 + 3];
          A0[g] = f4fma(xa0[j], wv4, A0[g]);
          A1[g] = f4fma(xa1[j], wv4, A1[g]);
        }
      }
    }
  }
  int oh0 = 2 * mh0 + ra, ow0 = 2 * mw0 + rb;
  size_t ob0 = ((n0 + img) * 196 + (size_t)(oh0 * 14 + ow0)) * 32;
#pragma unroll
  for (int g = 0; g < 8; ++g) {
    float4 bg = *(const float4*)&db1[g * 4];
    *(float4*)&d1[ob0 + g * 4] = f4relu(f4addrn(A0[g], bg));
  }
  if (v1) {
    int oh1 = 2 * mh1 + ra, ow1 = 2 * mw1 + rb;
    size_t ob1 = ((n0 + img) * 196 + (size_t)(oh1 * 14 + ow1)) * 32;
#pragma unroll
    for (int g = 0; g < 8; ++g) {
      float4 bg = *(const float4*)&db1[g * 4];
      *(float4*)&d1[ob1 + g * 4] = f4relu(f4addrn(A1[g], bg));
    }
  }
}

// ---- K7: deconv2 4x4 s2 p2, 32->1, sigmoid -> recon NCHW -------------------
__global__ __launch_bounds__(256) void k7_deconv2(const float* __restrict__ d1,
                                                  const float* __restrict__ dw2,
                                                  const float* __restrict__ db2,
                                                  float* __restrict__ recon) {
  __shared__ float xs[196 * 36];
  __shared__ float wl[512];
  int n = blockIdx.x, t = threadIdx.x;
  for (int j = t; j < 6272; j += 256) xs[(j >> 5) * 36 + (j & 31)] = d1[(size_t)n * 6272 + j];
  for (int j = t; j < 512; j += 256) wl[j] = dw2[j];
  __syncthreads();
  float bias = db2[0];
  for (int j = t; j < 392; j += 256) {
    int ra = j / 196, rem = j % 196;
    int mh = rem / 14, mw = rem % 14;
    float acc0 = bias, acc1 = bias;
    bool vm = (mw >= 1), vp = (mw + 1 < 14);
#pragma unroll
    for (int th = 0; th < 2; ++th) {
      int ih = mh + th - 1 + ra;
      if (ih < 0 || ih >= 14) continue;
      int kh = 2 * th + ra;
#pragma unroll
      for (int ci = 0; ci < 32; ci += 4) {
        float4 z4 = make_float4(0.f, 0.f, 0.f, 0.f);
        float4 xm = vm ? *(float4*)&xs[(ih * 14 + mw - 1) * 36 + ci] : z4;
        float4 x0 = *(float4*)&xs[(ih * 14 + mw) * 36 + ci];
        float4 xp = vp ? *(float4*)&xs[(ih * 14 + mw + 1) * 36 + ci] : z4;
        float4 wk0 = *(float4*)&wl[(kh * 4 + 0) * 32 + ci];
        float4 wk1 = *(float4*)&wl[(kh * 4 + 1) * 32 + ci];
        float4 wk2 = *(float4*)&wl[(kh * 4 + 2) * 32 + ci];
        float4 wk3 = *(float4*)&wl[(kh * 4 + 3) * 32 + ci];
        acc0 = fmaf(xm.x, wk0.x, acc0); acc0 = fmaf(xm.y, wk0.y, acc0);
        acc0 = fmaf(xm.z, wk0.z, acc0); acc0 = fmaf(xm.w, wk0.w, acc0);
        acc0 = fmaf(x0.x, wk2.x, acc0); acc0 = fmaf(x0.y, wk2.y, acc0);
        acc0 = fmaf(x0.z, wk2.z, acc0); acc0 = fmaf(x0.w, wk2.w, acc0);
        acc1 = fmaf(x0.x, wk1.x, acc1); acc1 = fmaf(x0.y, wk1.y, acc1);
        acc1 = fmaf(x0.z, wk1.z, acc1); acc1 = fmaf(x0.w, wk1.w, acc1);
        acc1 = fmaf(xp.x, wk3.x, acc1); acc1 = fmaf(xp.y, wk3.y, acc1);
        acc1 = fmaf(xp.z, wk3.z, acc1); acc1 = fmaf(xp.w, wk3.w, acc1);
      }
    }
    float r0 = 1.f / (1.f + __expf(-acc0));
    float r1 = 1.f / (1.f + __expf(-acc1));
    int oh = 2 * mh + ra;
    *(float2*)&recon[(size_t)n * 784 + oh * 28 + 2 * mw] = make_float2(r0, r1);
  }
}

extern "C" void kernel_launch(void* const* d_in, const int* in_sizes, int n_in,
                              void* d_out, int out_size, void* d_ws, size_t ws_size,
                              hipStream_t stream) {
  const float* x   = (const float*)d_in[0];
  const float* w1  = (const float*)d_in[1];
  const float* b1  = (const float*)d_in[2];
  const float* w2  = (const float*)d_in[3];
  const float* b2  = (const float*)d_in[4];
  const float* w3  = (const float*)d_in[5];
  const float* b3  = (const float*)d_in[6];
  const float* cb  = (const float*)d_in[7];
  const float* dw0 = (const float*)d_in[8];
  const float* db0 = (const float*)d_in[9];
  const float* dw1 = (const float*)d_in[10];
  const float* db1 = (const float*)d_in[11];
  const float* dw2 = (const float*)d_in[12];
  const float* db2 = (const float*)d_in[13];
  float* out = (float*)d_out;
  float* ws  = (float*)d_ws;

  float* h1   = ws;                 // 25,690,112 (reused as d1)
  float* h2   = ws + 25690112;      // 12,845,056 (reused as zq_nhwc)
  float* zb   = ws + 38535168;      // 12,845,056 z_nhwc (reused as d0)
  float* cn   = ws + 51380224;      // 512
  float* loss = ws + 51380736;      // 1

  float* recon   = out;
  float* zout    = out + 3211264;
  float* zqout   = out + 16056320;
  float* lossout = out + 28901376;
  float* idxout  = out + 28901377;

  k0_init<<<1, 256, 0, stream>>>(cb, cn, loss);
  k1_conv1<<<NB, 256, 0, stream>>>(x, w1, b1, h1);
  k2_conv2<<<NB / 2, 256, 0, stream>>>(h1, w2, b2, h2);
  k_pw<<<784, 256, 0, stream>>>(h2, w3, b3, zb);                 // z = h2 @ w3 + b3
  k4_vq<<<784, 128, 0, stream>>>(zb, cb, cn, h2, zout, zqout, idxout, loss);
  k_lossfin<<<1, 64, 0, stream>>>(loss, lossout);
  k_pw<<<784, 256, 0, stream>>>(h2, dw0, db0, zb);               // d0 = zq @ dw0 + db0
  k6_deconv1<<<NB / 2, 256, 0, stream>>>(zb, dw1, db1, h1);
  k7_deconv2<<<NB, 256, 0, stream>>>(h1, dw2, db2, recon);
}

// Round 10
// 1086.647 us; speedup vs baseline: 1.0730x; 1.0141x over previous
//
#include <hip/hip_runtime.h>

// ============================================================================
// VQ-VAE forward, MI355X fp32. Internal layout NHWC; outputs NCHW.
// B=4096. x(4096,1,28,28) -> h1(4096,14,14,32) -> h2(4096,7,7,64)
//   -> z -> VQ(512 codes, D=64) -> d0 -> d1(4096,14,14,32) -> recon.
// VQ argmin reproduces np fp32 semantics exactly:
//   dist = fl( fl(SZ + SC_k) - 2*dot(z,c_k) ), SZ/SC via numpy pairwise-8,
//   dot via sequential-K fma (BLAS order), first-min-wins tie break.
// R2: unrolled tap loop -> 256-VGPR cap -> scratch spill -> 12 GB HBM.
// R4: k2/k6 LDS-read bound -> s_load weights + big register tiles.
// R6 (REVERTED): per-thread-contiguous global access catastrophic.
// R7: global-cb loop L2-stream bound (latency-exposed at low occ).
// R8: cb LDS chunks, 256thr x 2pt: VGPR=164 (arch zr), 421us, Occ 9%.
// R9-R11: 1pt/thr: zr never promoted (VGPR=52, LDS-bound 410us).
// R12: chunk-clobber 1pt/thr: zr -> AGPRs, accvgpr_read tax, 316us.
// R13-R15 (dead): manual s_load serialized; "v"/"a" asm constraints can't
//   move allocation; gfx950 VOP2 can't source AGPRs.
// R16 (BEST PASSING, 321us k4 / 1102us total): 2pt x 128thr x 784 blocks,
//   VGPR=128, VALU-busy 130us. Shared floor: broadcast ds_read stream
//   (~251us/CU of LDS pipe) + staging writes on the same pipe.
// R17 (FAILED, REVERTED): cb read from global in k loop -> idx flipped
//   (absmax 393) while z passed. Arithmetic was textually identical;
//   mechanism UNEXPLAINED (tie-flip sensitivity). Global-cb path closed
//   until explained with disasm. Lesson: do not gamble final state on an
//   unexplained transformation.
// R18 (this round): R16 verbatim + float4-vectorized chunk staging
//   (ds_write_b128/global_load_dwordx4 instead of scalar: 4096->1024 ops
//   per chunk per block, ~115us of per-CU LDS-pipe write cycles removed).
//   Same bits, same barriers, k loop untouched.
// Workspace (floats): h1/d1 @0 (25,690,112) | h2/zq @25,690,112 (12,845,056)
//   | z/d0 @38,535,168 (12,845,056) | cn @51,380,224 (512) | loss @51,380,736
// Out (floats): recon@0, z@3,211,264, z_q@16,056,320, loss@28,901,376,
//   idx@28,901,377 (200,704)
// ============================================================================

#define NB 4096

__device__ __forceinline__ float4 f4fma(float s, float4 w, float4 a) {
  a.x = fmaf(s, w.x, a.x); a.y = fmaf(s, w.y, a.y);
  a.z = fmaf(s, w.z, a.z); a.w = fmaf(s, w.w, a.w);
  return a;
}
__device__ __forceinline__ float4 f4relu(float4 a) {
  a.x = fmaxf(a.x, 0.f); a.y = fmaxf(a.y, 0.f);
  a.z = fmaxf(a.z, 0.f); a.w = fmaxf(a.w, 0.f);
  return a;
}
__device__ __forceinline__ float4 f4addrn(float4 a, float4 b) {
  a.x = __fadd_rn(a.x, b.x); a.y = __fadd_rn(a.y, b.y);
  a.z = __fadd_rn(a.z, b.z); a.w = __fadd_rn(a.w, b.w);
  return a;
}

// numpy pairwise-8 sum of squares over 64 contiguous values
__device__ __forceinline__ float np_sumsq64(const float* v) {
  float r[8];
#pragma unroll
  for (int j = 0; j < 8; ++j) r[j] = __fmul_rn(v[j], v[j]);
#pragma unroll
  for (int i = 8; i < 64; i += 8)
#pragma unroll
    for (int j = 0; j < 8; ++j) r[j] = __fadd_rn(r[j], __fmul_rn(v[i + j], v[i + j]));
  return __fadd_rn(__fadd_rn(__fadd_rn(r[0], r[1]), __fadd_rn(r[2], r[3])),
                   __fadd_rn(__fadd_rn(r[4], r[5]), __fadd_rn(r[6], r[7])));
}

// ---- K0: codebook norms (numpy-order) + zero loss accumulator --------------
__global__ __launch_bounds__(256) void k0_init(const float* __restrict__ cb,
                                               float* __restrict__ cn,
                                               float* __restrict__ loss) {
  int t = threadIdx.x;
  if (t == 0) *loss = 0.f;
  for (int k = t; k < 512; k += 256) cn[k] = np_sumsq64(&cb[k * 64]);
}

// ---- K1: conv1 4x4 s2 p1, 1->32, bias-after, ReLU. out h1 NHWC -------------
__global__ __launch_bounds__(256) void k1_conv1(const float* __restrict__ x,
                                                const float* __restrict__ w1,
                                                const float* __restrict__ b1,
                                                float* __restrict__ h1) {
  __shared__ float xs[784];
  __shared__ float wl[512];
  __shared__ float bs[32];
  int n = blockIdx.x, t = threadIdx.x;
  for (int j = t; j < 784; j += 256) xs[j] = x[n * 784 + j];
  for (int j = t; j < 512; j += 256) wl[j] = w1[j];
  if (t < 32) bs[t] = b1[t];
  __syncthreads();
  int c = t & 31, pg = t >> 5;
  for (int s = pg; s < 196; s += 8) {
    int oh = s / 14, ow = s % 14;
    float acc = 0.f;
#pragma unroll
    for (int kh = 0; kh < 4; ++kh) {
      int ih = 2 * oh - 1 + kh;
      if (ih < 0 || ih >= 28) continue;
#pragma unroll
      for (int kw = 0; kw < 4; ++kw) {
        int iw = 2 * ow - 1 + kw;
        if (iw < 0 || iw >= 28) continue;
        acc = fmaf(xs[ih * 28 + iw], wl[(kh * 4 + kw) * 32 + c], acc);
      }
    }
    acc = __fadd_rn(acc, bs[c]);
    h1[(n * 196 + s) * 32 + c] = fmaxf(acc, 0.f);
  }
}

// ---- K2: conv2 4x4 s2 p1, 32->64, bias-after, ReLU. NHWC -------------------
__global__ __launch_bounds__(256) void k2_conv2(const float* __restrict__ h1,
                                                const float* __restrict__ w2,
                                                const float* __restrict__ b2,
                                                float* __restrict__ h2) {
  __shared__ float4 xs4[2 * 2049];
  int nb = blockIdx.x, t = threadIdx.x;
  size_t n0 = (size_t)nb * 2;
  for (int j = t; j < 4098; j += 256) xs4[j] = make_float4(0.f, 0.f, 0.f, 0.f);
  __syncthreads();
  for (int j = t; j < 1568; j += 256) {
    int p = j >> 3, c4 = j & 7;
    int ihp = p / 14 + 1, iwp = p % 14 + 1;
    int chunk = (c4 * 16 + ihp) * 16 + (iwp & 1) * 8 + (iwp >> 1);
    xs4[chunk] = *(const float4*)(h1 + n0 * 6272 + p * 32 + c4 * 4);
    xs4[2049 + chunk] = *(const float4*)(h1 + (n0 + 1) * 6272 + p * 32 + c4 * 4);
  }
  __syncthreads();
  int l = t & 63;
  int co0 = __builtin_amdgcn_readfirstlane((t >> 6) * 16);
  int img = l >> 5, pt = l & 31;
  int oh0 = pt >> 3, ow = pt & 7;
  int imgoff = img * 2049;
  bool v0 = (ow < 7);
  bool v1 = (ow < 7) && (oh0 + 4 < 7);
  float4 A0[4], A1[4];
#pragma unroll
  for (int g = 0; g < 4; ++g) { A0[g] = make_float4(0.f, 0.f, 0.f, 0.f); A1[g] = A0[g]; }
#pragma unroll 1
  for (int kk = 0; kk < 16; ++kk) {
    int kh = kk >> 2, kw = kk & 3;
    int cc = 2 * ow + kw; if (cc > 15) cc = 15;
    int off = (cc & 1) * 8 + (cc >> 1);
    int rc0 = 2 * oh0 + kh;
    int rc1 = rc0 + 8; if (rc1 > 15) rc1 = 15;
    int b0 = imgoff + rc0 * 16 + off;
    int b1 = imgoff + rc1 * 16 + off;
    int wb = __builtin_amdgcn_readfirstlane(kk * 2048 + co0);
#pragma unroll 2
    for (int c4 = 0; c4 < 8; ++c4) {
      float4 x0 = xs4[b0 + c4 * 256];
      float4 x1 = xs4[b1 + c4 * 256];
      float xa0[4] = {x0.x, x0.y, x0.z, x0.w};
      float xa1[4] = {x1.x, x1.y, x1.z, x1.w};
      const float* wk = w2 + wb + c4 * 256;
#pragma unroll
      for (int j = 0; j < 4; ++j) {
#pragma unroll
        for (int g = 0; g < 4; ++g) {
          float4 wv4;
          wv4.x = wk[j * 64 + g * 4 + 0]; wv4.y = wk[j * 64 + g * 4 + 1];
          wv4.z = wk[j * 64 + g * 4 + 2]; wv4.w = wk[j * 64 + g * 4 + 3];
          A0[g] = f4fma(xa0[j], wv4, A0[g]);
          A1[g] = f4fma(xa1[j], wv4, A1[g]);
        }
      }
    }
  }
  float4 bias[4];
#pragma unroll
  for (int g = 0; g < 4; ++g) bias[g] = *(const float4*)&b2[co0 + g * 4];
  if (v0) {
    size_t ob = ((n0 + img) * 49 + oh0 * 7 + ow) * 64 + co0;
#pragma unroll
    for (int g = 0; g < 4; ++g)
      *(float4*)&h2[ob + g * 4] = f4relu(f4addrn(A0[g], bias[g]));
  }
  if (v1) {
    size_t ob = ((n0 + img) * 49 + (oh0 + 4) * 7 + ow) * 64 + co0;
#pragma unroll
    for (int g = 0; g < 4; ++g)
      *(float4*)&h2[ob + g * 4] = f4relu(f4addrn(A1[g], bias[g]));
  }
}

// ---- K_pw: 1x1 conv 64->64, bias-after (no act). NHWC ----------------------
__global__ __launch_bounds__(256) void k_pw(const float* __restrict__ xin,
                                            const float* __restrict__ w,     // [ci][co]
                                            const float* __restrict__ bias,
                                            float* __restrict__ yout) {
  __shared__ float tile[256 * 65];
  int t = threadIdx.x;
  long m0 = (long)blockIdx.x * 256;
  for (int j = t; j < 16384; j += 256) tile[(j >> 6) * 65 + (j & 63)] = xin[m0 * 64 + j];
  __syncthreads();
  float xr[64];
#pragma unroll
  for (int ci = 0; ci < 64; ++ci) xr[ci] = tile[t * 65 + ci];
  for (int g = 0; g < 4; ++g) {
    float4 z4 = make_float4(0.f, 0.f, 0.f, 0.f);
    float4 a0 = z4, a1 = z4, a2 = z4, a3 = z4;
#pragma unroll
    for (int ci = 0; ci < 64; ++ci) {
      float xv = xr[ci];
      const float* wr = &w[ci * 64 + g * 16];
      a0 = f4fma(xv, *(const float4*)&wr[0], a0);
      a1 = f4fma(xv, *(const float4*)&wr[4], a1);
      a2 = f4fma(xv, *(const float4*)&wr[8], a2);
      a3 = f4fma(xv, *(const float4*)&wr[12], a3);
    }
    a0 = f4addrn(a0, *(const float4*)&bias[g * 16 + 0]);
    a1 = f4addrn(a1, *(const float4*)&bias[g * 16 + 4]);
    a2 = f4addrn(a2, *(const float4*)&bias[g * 16 + 8]);
    a3 = f4addrn(a3, *(const float4*)&bias[g * 16 + 12]);
    float* dst = &tile[t * 65 + g * 16];
    dst[0] = a0.x; dst[1] = a0.y; dst[2] = a0.z; dst[3] = a0.w;
    dst[4] = a1.x; dst[5] = a1.y; dst[6] = a1.z; dst[7] = a1.w;
    dst[8] = a2.x; dst[9] = a2.y; dst[10] = a2.z; dst[11] = a2.w;
    dst[12] = a3.x; dst[13] = a3.y; dst[14] = a3.z; dst[15] = a3.w;
  }
  __syncthreads();
  for (int j = t; j < 16384; j += 256) yout[m0 * 64 + j] = tile[(j >> 6) * 65 + (j & 63)];
}

// ---- K4: VQ. 128 threads, 2 points/thread = 256 pts/block, 784 blocks ------
// R16 structure (last passing): arch-VGPR zr (2pt/thread shape), cb in LDS
// 16KB chunks clobbering the z tile, broadcast conflict-free ds_read_b128,
// 4 fma chains. R18: chunk staging vectorized to float4 (ds_write_b128 +
// global_load_dwordx4, 4x fewer ops on the LDS pipe's write side).
// np-exact per-code fma order and k-ascending first-min-wins compares.
__global__ __launch_bounds__(128, 2) void k4_vq(const float* __restrict__ zin,
                                                const float* __restrict__ cb,
                                                const float* __restrict__ cn,
                                                float* __restrict__ zq_nhwc,
                                                float* __restrict__ outz,
                                                float* __restrict__ outzq,
                                                float* __restrict__ outidx,
                                                float* __restrict__ loss) {
  __shared__ float lds[8320];   // 128*65 tile  |  cbs[0..4096) + cns[4096..4608)
  __shared__ float red[2];
  int t = threadIdx.x;          // 0..127
  size_t m0 = (size_t)blockIdx.x * 256;
  float zrA[64], zrB[64];

#define K4_STAGE_IN(S, ZR)                                                    \
  {                                                                           \
    __syncthreads();                                                          \
    const float* src = zin + (m0 + (S) * 128) * 64;                           \
    for (int j4 = t; j4 < 2048; j4 += 128) {                                  \
      int row = j4 >> 4, col = (j4 & 15) * 4;                                 \
      *(float4*)&lds[row * 65 + col] = *(const float4*)(src + j4 * 4);        \
    }                                                                         \
    __syncthreads();                                                          \
    _Pragma("unroll")                                                         \
    for (int ci = 0; ci < 64; ci += 4) {                                      \
      float4 v = *(float4*)&lds[t * 65 + ci];                                 \
      ZR[ci] = v.x; ZR[ci + 1] = v.y; ZR[ci + 2] = v.z; ZR[ci + 3] = v.w;     \
    }                                                                         \
  }

  K4_STAGE_IN(0, zrA)
  K4_STAGE_IN(1, zrB)

  float szA = np_sumsq64(zrA), szB = np_sumsq64(zrB);
  float minA = 3.4e38f, minB = 3.4e38f;
  int miA = 0, miB = 0;
#pragma unroll 1
  for (int ch = 0; ch < 8; ++ch) {
    __syncthreads();
    // float4 staging: 1024 ds_write_b128 / global_load_dwordx4 per chunk
    // (was 4096 scalar) -- same bits, 4x fewer ops on the LDS pipe.
    for (int j4 = t; j4 < 1024; j4 += 128)
      *(float4*)&lds[j4 * 4] = *(const float4*)&cb[ch * 4096 + j4 * 4];   // clobbers z tile
    if (ch == 0 && t < 128)
      *(float4*)&lds[4096 + t * 4] = *(const float4*)&cn[t * 4];
    __syncthreads();
#pragma unroll 1
    for (int k = 0; k < 64; k += 2) {
      const float* r0 = &lds[k * 64];
      const float* r1 = r0 + 64;
      float dA0 = 0.f, dA1 = 0.f, dB0 = 0.f, dB1 = 0.f;
#pragma unroll
      for (int ci = 0; ci < 64; ci += 4) {
        float4 c0 = *(const float4*)(r0 + ci);
        float4 c1 = *(const float4*)(r1 + ci);
        dA0 = fmaf(zrA[ci], c0.x, dA0); dA0 = fmaf(zrA[ci + 1], c0.y, dA0);
        dA0 = fmaf(zrA[ci + 2], c0.z, dA0); dA0 = fmaf(zrA[ci + 3], c0.w, dA0);
        dB0 = fmaf(zrB[ci], c0.x, dB0); dB0 = fmaf(zrB[ci + 1], c0.y, dB0);
        dB0 = fmaf(zrB[ci + 2], c0.z, dB0); dB0 = fmaf(zrB[ci + 3], c0.w, dB0);
        dA1 = fmaf(zrA[ci], c1.x, dA1); dA1 = fmaf(zrA[ci + 1], c1.y, dA1);
        dA1 = fmaf(zrA[ci + 2], c1.z, dA1); dA1 = fmaf(zrA[ci + 3], c1.w, dA1);
        dB1 = fmaf(zrB[ci], c1.x, dB1); dB1 = fmaf(zrB[ci + 1], c1.y, dB1);
        dB1 = fmaf(zrB[ci + 2], c1.z, dB1); dB1 = fmaf(zrB[ci + 3], c1.w, dB1);
      }
      float cn0 = lds[4096 + ch * 64 + k];
      float cn1 = lds[4096 + ch * 64 + k + 1];
      float qA0 = __fsub_rn(__fadd_rn(szA, cn0), __fmul_rn(2.f, dA0));
      float qA1 = __fsub_rn(__fadd_rn(szA, cn1), __fmul_rn(2.f, dA1));
      float qB0 = __fsub_rn(__fadd_rn(szB, cn0), __fmul_rn(2.f, dB0));
      float qB1 = __fsub_rn(__fadd_rn(szB, cn1), __fmul_rn(2.f, dB1));
      int kk = ch * 64 + k;
      if (qA0 < minA) { minA = qA0; miA = kk; }
      if (qA1 < minA) { minA = qA1; miA = kk + 1; }
      if (qB0 < minB) { minB = qB0; miB = kk; }
      if (qB1 < minB) { minB = qB1; miB = kk + 1; }
    }
  }

  // idx + z NCHW scatter (zr still live)
  outidx[m0 + t] = (float)miA;
  outidx[m0 + 128 + t] = (float)miB;
  {
    unsigned mA = (unsigned)(m0 + t), mB = (unsigned)(m0 + 128 + t);
    unsigned nA = mA / 49u, spA = mA % 49u;
    unsigned nB = mB / 49u, spB = mB % 49u;
    float* zoA = outz + (size_t)nA * 3136 + spA;
    float* zoB = outz + (size_t)nB * 3136 + spB;
#pragma unroll
    for (int ci = 0; ci < 64; ++ci) { zoA[ci * 49] = zrA[ci]; zoB[ci * 49] = zrB[ci]; }
  }

  float lsum = 0.f;
#define K4_STAGE_OUT(S, ZR, MI)                                               \
  {                                                                           \
    __syncthreads();                                                          \
    {                                                                         \
      unsigned mm = (unsigned)(m0 + (S) * 128 + t);                           \
      unsigned nn = mm / 49u, ss = mm % 49u;                                  \
      float* qo = outzq + (size_t)nn * 3136 + ss;                             \
      const float* qr = cb + (size_t)(MI) * 64;                               \
      _Pragma("unroll")                                                       \
      for (int ci = 0; ci < 64; ci += 4) {                                    \
        float4 q4 = *(const float4*)(qr + ci);                                \
        *(float4*)&lds[t * 65 + ci] = q4;                                     \
        qo[(ci + 0) * 49] = q4.x; qo[(ci + 1) * 49] = q4.y;                   \
        qo[(ci + 2) * 49] = q4.z; qo[(ci + 3) * 49] = q4.w;                   \
        float e0 = q4.x - ZR[ci], e1 = q4.y - ZR[ci + 1];                     \
        float e2 = q4.z - ZR[ci + 2], e3 = q4.w - ZR[ci + 3];                 \
        lsum = fmaf(e0, e0, lsum); lsum = fmaf(e1, e1, lsum);                 \
        lsum = fmaf(e2, e2, lsum); lsum = fmaf(e3, e3, lsum);                 \
      }                                                                       \
    }                                                                         \
    __syncthreads();                                                          \
    float* dstg = zq_nhwc + (m0 + (S) * 128) * 64;                            \
    for (int j4 = t; j4 < 2048; j4 += 128) {                                  \
      int row = j4 >> 4, col = (j4 & 15) * 4;                                 \
      *(float4*)(dstg + j4 * 4) = *(float4*)&lds[row * 65 + col];             \
    }                                                                         \
  }
  K4_STAGE_OUT(0, zrA, miA)
  K4_STAGE_OUT(1, zrB, miB)
#undef K4_STAGE_IN
#undef K4_STAGE_OUT
#pragma unroll
  for (int off = 32; off > 0; off >>= 1) lsum += __shfl_down(lsum, off);
  int wid = t >> 6, lane = t & 63;
  if (lane == 0) red[wid] = lsum;
  __syncthreads();
  if (t == 0) atomicAdd(loss, red[0] + red[1]);
}

// ---- K4b: finalize loss ----------------------------------------------------
__global__ __launch_bounds__(64) void k_lossfin(const float* __restrict__ loss,
                                                float* __restrict__ out) {
  if (threadIdx.x == 0) out[0] = loss[0] * (1.25f / 12845056.f);
}

// ---- K6: deconv1 4x4 s2 p2 (lhs_dilation), 64->32, ReLU. NHWC --------------
__global__ __launch_bounds__(256) void k6_deconv1(const float* __restrict__ d0,
                                                  const float* __restrict__ dw1,
                                                  const float* __restrict__ db1,
                                                  float* __restrict__ d1) {
  __shared__ float4 xs4[2 * 1297];
  int nb = blockIdx.x, t = threadIdx.x;
  size_t n0 = (size_t)nb * 2;
  for (int j = t; j < 2594; j += 256) xs4[j] = make_float4(0.f, 0.f, 0.f, 0.f);
  __syncthreads();
  for (int j = t; j < 784; j += 256) {
    int p = j >> 4, c4 = j & 15;
    int chunk = c4 * 81 + (p / 7 + 1) * 9 + (p % 7 + 1);
    xs4[chunk] = *(const float4*)(d0 + n0 * 3136 + p * 64 + c4 * 4);
    xs4[1297 + chunk] = *(const float4*)(d0 + (n0 + 1) * 3136 + p * 64 + c4 * 4);
  }
  __syncthreads();
  int l = t & 63;
  int ph = __builtin_amdgcn_readfirstlane(t >> 6);
  int ra = ph >> 1, rb = ph & 1;
  int img = l >> 5, pt = l & 31;
  bool v1 = (pt + 32 < 49);
  int p1 = v1 ? pt + 32 : 48;
  int mh0 = pt / 7, mw0 = pt % 7;
  int mh1 = p1 / 7, mw1 = p1 % 7;
  int imgoff = img * 1297;
  float4 A0[8], A1[8];
#pragma unroll
  for (int g = 0; g < 8; ++g) { A0[g] = make_float4(0.f, 0.f, 0.f, 0.f); A1[g] = A0[g]; }
#pragma unroll 1
  for (int tap = 0; tap < 4; ++tap) {
    int th = tap >> 1, tw = tap & 1;
    int kh = 2 * th + ra, kw = 2 * tw + rb;
    int b0 = imgoff + (mh0 + th + ra) * 9 + (mw0 + tw + rb);
    int b1 = imgoff + (mh1 + th + ra) * 9 + (mw1 + tw + rb);
    int wb = __builtin_amdgcn_readfirstlane((kh * 4 + kw) * 2048);
#pragma unroll 1
    for (int c4 = 0; c4 < 16; ++c4) {
      float4 x0 = xs4[b0 + c4 * 81];
      float4 x1 = xs4[b1 + c4 * 81];
      float xa0[4] = {x0.x, x0.y, x0.z, x0.w};
      float xa1[4] = {x1.x, x1.y, x1.z, x1.w};
      const float* wk = dw1 + wb + c4 * 128;
#pragma unroll
      for (int j = 0; j < 4; ++j) {
#pragma unroll
        for (int g = 0; g < 8; ++g) {
          float4 wv4;
          wv4.x = wk[j * 32 + g * 4 + 0]; wv4.y = wk[j * 32 + g * 4 + 1];
          wv4.z = wk[j * 32 + g * 4 + 2]; wv4.w = wk[j * 32 + g * 4 + 3];
          A0[g] = f4fma(xa0[j], wv4, A0[g]);
          A1[g] = f4fma(xa1[j], wv4, A1[g]);
        }
      }
    }
  }
  int oh0 = 2 * mh0 + ra, ow0 = 2 * mw0 + rb;
  size_t ob0 = ((n0 + img) * 196 + (size_t)(oh0 * 14 + ow0)) * 32;
#pragma unroll
  for (int g = 0; g < 8; ++g) {
    float4 bg = *(const float4*)&db1[g * 4];
    *(float4*)&d1[ob0 + g * 4] = f4relu(f4addrn(A0[g], bg));
  }
  if (v1) {
    int oh1 = 2 * mh1 + ra, ow1 = 2 * mw1 + rb;
    size_t ob1 = ((n0 + img) * 196 + (size_t)(oh1 * 14 + ow1)) * 32;
#pragma unroll
    for (int g = 0; g < 8; ++g) {
      float4 bg = *(const float4*)&db1[g * 4];
      *(float4*)&d1[ob1 + g * 4] = f4relu(f4addrn(A1[g], bg));
    }
  }
}

// ---- K7: deconv2 4x4 s2 p2, 32->1, sigmoid -> recon NCHW -------------------
__global__ __launch_bounds__(256) void k7_deconv2(const float* __restrict__ d1,
                                                  const float* __restrict__ dw2,
                                                  const float* __restrict__ db2,
                                                  float* __restrict__ recon) {
  __shared__ float xs[196 * 36];
  __shared__ float wl[512];
  int n = blockIdx.x, t = threadIdx.x;
  for (int j = t; j < 6272; j += 256) xs[(j >> 5) * 36 + (j & 31)] = d1[(size_t)n * 6272 + j];
  for (int j = t; j < 512; j += 256) wl[j] = dw2[j];
  __syncthreads();
  float bias = db2[0];
  for (int j = t; j < 392; j += 256) {
    int ra = j / 196, rem = j % 196;
    int mh = rem / 14, mw = rem % 14;
    float acc0 = bias, acc1 = bias;
    bool vm = (mw >= 1), vp = (mw + 1 < 14);
#pragma unroll
    for (int th = 0; th < 2; ++th) {
      int ih = mh + th - 1 + ra;
      if (ih < 0 || ih >= 14) continue;
      int kh = 2 * th + ra;
#pragma unroll
      for (int ci = 0; ci < 32; ci += 4) {
        float4 z4 = make_float4(0.f, 0.f, 0.f, 0.f);
        float4 xm = vm ? *(float4*)&xs[(ih * 14 + mw - 1) * 36 + ci] : z4;
        float4 x0 = *(float4*)&xs[(ih * 14 + mw) * 36 + ci];
        float4 xp = vp ? *(float4*)&xs[(ih * 14 + mw + 1) * 36 + ci] : z4;
        float4 wk0 = *(float4*)&wl[(kh * 4 + 0) * 32 + ci];
        float4 wk1 = *(float4*)&wl[(kh * 4 + 1) * 32 + ci];
        float4 wk2 = *(float4*)&wl[(kh * 4 + 2) * 32 + ci];
        float4 wk3 = *(float4*)&wl[(kh * 4 + 3) * 32 + ci];
        acc0 = fmaf(xm.x, wk0.x, acc0); acc0 = fmaf(xm.y, wk0.y, acc0);
        acc0 = fmaf(xm.z, wk0.z, acc0); acc0 = fmaf(xm.w, wk0.w, acc0);
        acc0 = fmaf(x0.x, wk2.x, acc0); acc0 = fmaf(x0.y, wk2.y, acc0);
        acc0 = fmaf(x0.z, wk2.z, acc0); acc0 = fmaf(x0.w, wk2.w, acc0);
        acc1 = fmaf(x0.x, wk1.x, acc1); acc1 = fmaf(x0.y, wk1.y, acc1);
        acc1 = fmaf(x0.z, wk1.z, acc1); acc1 = fmaf(x0.w, wk1.w, acc1);
        acc1 = fmaf(xp.x, wk3.x, acc1); acc1 = fmaf(xp.y, wk3.y, acc1);
        acc1 = fmaf(xp.z, wk3.z, acc1); acc1 = fmaf(xp.w, wk3.w, acc1);
      }
    }
    float r0 = 1.f / (1.f + __expf(-acc0));
    float r1 = 1.f / (1.f + __expf(-acc1));
    int oh = 2 * mh + ra;
    *(float2*)&recon[(size_t)n * 784 + oh * 28 + 2 * mw] = make_float2(r0, r1);
  }
}

extern "C" void kernel_launch(void* const* d_in, const int* in_sizes, int n_in,
                              void* d_out, int out_size, void* d_ws, size_t ws_size,
                              hipStream_t stream) {
  const float* x   = (const float*)d_in[0];
  const float* w1  = (const float*)d_in[1];
  const float* b1  = (const float*)d_in[2];
  const float* w2  = (const float*)d_in[3];
  const float* b2  = (const float*)d_in[4];
  const float* w3  = (const float*)d_in[5];
  const float* b3  = (const float*)d_in[6];
  const float* cb  = (const float*)d_in[7];
  const float* dw0 = (const float*)d_in[8];
  const float* db0 = (const float*)d_in[9];
  const float* dw1 = (const float*)d_in[10];
  const float* db1 = (const float*)d_in[11];
  const float* dw2 = (const float*)d_in[12];
  const float* db2 = (const float*)d_in[13];
  float* out = (float*)d_out;
  float* ws  = (float*)d_ws;

  float* h1   = ws;                 // 25,690,112 (reused as d1)
  float* h2   = ws + 25690112;      // 12,845,056 (reused as zq_nhwc)
  float* zb   = ws + 38535168;      // 12,845,056 z_nhwc (reused as d0)
  float* cn   = ws + 51380224;      // 512
  float* loss = ws + 51380736;      // 1

  float* recon   = out;
  float* zout    = out + 3211264;
  float* zqout   = out + 16056320;
  float* lossout = out + 28901376;
  float* idxout  = out + 28901377;

  k0_init<<<1, 256, 0, stream>>>(cb, cn, loss);
  k1_conv1<<<NB, 256, 0, stream>>>(x, w1, b1, h1);
  k2_conv2<<<NB / 2, 256, 0, stream>>>(h1, w2, b2, h2);
  k_pw<<<784, 256, 0, stream>>>(h2, w3, b3, zb);                 // z = h2 @ w3 + b3
  k4_vq<<<784, 128, 0, stream>>>(zb, cb, cn, h2, zout, zqout, idxout, loss);
  k_lossfin<<<1, 64, 0, stream>>>(loss, lossout);
  k_pw<<<784, 256, 0, stream>>>(h2, dw0, db0, zb);               // d0 = zq @ dw0 + db0
  k6_deconv1<<<NB / 2, 256, 0, stream>>>(zb, dw1, db1, h1);
  k7_deconv2<<<NB, 256, 0, stream>>>(h1, dw2, db2, recon);
}